// Round 10
// baseline (910.732 us; speedup 1.0000x reference)
//
#include <hip/hip_runtime.h>

typedef _Float16 half_t;
typedef _Float16 half8 __attribute__((ext_vector_type(8)));
typedef _Float16 half2_t __attribute__((ext_vector_type(2)));
typedef float f32x16 __attribute__((ext_vector_type(16)));
typedef float f32x4 __attribute__((ext_vector_type(4)));

#define DEVINL __device__ __forceinline__

// ---------- constants ----------
#define INV_S3 0.57735026918962576f   // 1/sqrt(3)
#define INV_S2 0.70710678118654752f   // 1/sqrt(2)
#define C_OLD  0.89442719099991588f   // 1/sqrt(1.25)
#define A_COLD 0.44721359549995794f   // 0.5/sqrt(1.25)
#define SC_ENV 0.05590169943749474f   // (1/sqrt(20)) * (1/4)
#define SC_FS  0.17677669529663688f   // 1/sqrt(32)
#define SC_FV  0.14433756729740643f   // 1/sqrt(48)
#define SC_OUT 0.03608439182435161f   // (1/4)/sqrt(48) — includes layer-1 fold scale
#define SSD 34                         // sS stride (halfs)
#define VPH 146                        // V stride (halfs)

DEVINL float silu_f(float x) { return x / (1.f + __expf(-x)); }

DEVINL float poly_cut(float u) {
    float u2 = u * u, u4 = u2 * u2, u6 = u4 * u2;
    float f = 1.f - 28.f * u6 + 48.f * u6 * u - 21.f * u6 * u2;
    return (u < 1.f) ? f : 0.f;
}

DEVINL float pkh(float a, float b) {
    half2_t h; h[0] = (half_t)a; h[1] = (half_t)b;
    return __builtin_bit_cast(float, h);
}
DEVINL float2 uph(float p) {
    half2_t h = __builtin_bit_cast(half2_t, p);
    return make_float2((float)h[0], (float)h[1]);
}
DEVINL half8 mk8(const float* w) {
    f32x4 v = {w[0], w[1], w[2], w[3]};
    return __builtin_bit_cast(half8, v);
}
DEVINL float ld_pk2(const half_t* p) {
    half2_t h; h[0] = p[0]; h[1] = p[1];
    return __builtin_bit_cast(float, h);
}
// ---- non-temporal streaming access (keep weights resident in L2) ----
DEVINL float ntl_f(const float* p) { return __builtin_nontemporal_load(p); }
DEVINL void nts_f(float v, float* p) { __builtin_nontemporal_store(v, p); }
DEVINL f32x4 ntl_f4(const void* p) {
    return __builtin_nontemporal_load((const f32x4*)p);
}
DEVINL void nts_h8(half8 v, half_t* p) {
    __builtin_nontemporal_store(v, (half8*)p);
}

// =====================================================================
// Edge-column MFMA stage: A = weights [M=features], B = edges (in regs).
// Weight pack: cell(mtile,kblk,m) at halfs[((mtile*KB+kblk)*32+m)*8+j]
// D: lane owns edge col n = lane&31; row f = (r&3) + 8*(r>>2) + 4*(lane>>5).
// =====================================================================
template <int KB>  // K/8
DEVINL f32x16 colstage(const half_t* __restrict__ Wg, const float* B, int mtile,
                       int nl, int q) {
    const half_t* ap = Wg + (((size_t)mtile * KB + q) * 32 + nl) * 8;
    f32x16 acc;
#pragma unroll
    for (int i = 0; i < 16; ++i) acc[i] = 0.f;
#pragma unroll
    for (int h = 0; h < KB / 2; ++h) {
        half8 a = *reinterpret_cast<const half8*>(ap + h * 512);
        acc = __builtin_amdgcn_mfma_f32_32x32x16_f16(a, mk8(B + h * 4), acc, 0, 0, 0);
    }
    return acc;
}

DEVINL void silu16(f32x16& a) {
#pragma unroll
    for (int i = 0; i < 16; ++i) a[i] = silu_f(a[i]);
}

// D (f32 regs) -> B-frag for next stage: two k-windows of 4 packed floats.
DEVINL void d2b(const f32x16& d, int lane, int q, float* wA, float* wB) {
    float pk[8];
#pragma unroll
    for (int a2 = 0; a2 < 4; ++a2) {
        pk[a2 * 2 + 0] = pkh(d[4 * a2 + 0], d[4 * a2 + 1]);
        pk[a2 * 2 + 1] = pkh(d[4 * a2 + 2], d[4 * a2 + 3]);
    }
#pragma unroll
    for (int t = 0; t < 2; ++t) {
        float k0 = q ? pk[(2 * t + 1) * 2 + 0] : pk[(2 * t) * 2 + 0];
        float k1 = q ? pk[(2 * t + 1) * 2 + 1] : pk[(2 * t) * 2 + 1];
        float s0 = q ? pk[(2 * t) * 2 + 0] : pk[(2 * t + 1) * 2 + 0];
        float s1 = q ? pk[(2 * t) * 2 + 1] : pk[(2 * t + 1) * 2 + 1];
        float r0 = __shfl(s0, lane ^ 32, 64);
        float r1 = __shfl(s1, lane ^ 32, 64);
        float* w = t ? wB : wA;
        w[0] = q ? r0 : k0;
        w[1] = q ? r1 : k1;
        w[2] = q ? k0 : r0;
        w[3] = q ? k1 : r1;
    }
}

// =====================================================================
__global__ __launch_bounds__(256) void k_zero(float* __restrict__ p, int n) {
    int i = blockIdx.x * 256 + threadIdx.x;
    if (i < n) p[i] = 0.f;
}

// =====================================================================
struct PackArgs {
    const float* src[14];
    half_t* dst[14];
    int K[14];
    int N[14];
};

__global__ __launch_bounds__(256) void k_pack(PackArgs pa) {
    int mi = blockIdx.y;
    int K = pa.K[mi], N = pa.N[mi];
    int Npad = (N + 31) & ~31;
    int KB = K >> 3;
    int cells = KB * Npad;
    int cell = blockIdx.x * 256 + threadIdx.x;
    if (cell >= cells) return;
    int nn = cell & 31, r2 = cell >> 5;
    int kblk = r2 % KB, ntile = r2 / KB;
    int n = ntile * 32 + nn;
    const float* W = pa.src[mi];
    half8 v;
#pragma unroll
    for (int j = 0; j < 8; ++j) {
        int k = kblk * 8 + j;
        v[j] = (half_t)((n < N) ? W[k * N + n] : 0.f);
    }
    *reinterpret_cast<half8*>(pa.dst[mi] + (size_t)cell * 8) = v;
}

// =====================================================================
// K1: front. 2 independent waves/block, 32 edges each, no LDS.
// =====================================================================
__global__ __launch_bounds__(128, 4) void k_edge_front(
    const float* __restrict__ g_ea, const float* __restrict__ g_na,
    const float* __restrict__ g_emb, const float* __restrict__ g_eu,
    const int* __restrict__ g_eidx,
    const half_t* __restrict__ b_w2b1, const half_t* __restrict__ b_w2b2,
    const half_t* __restrict__ b_e0w1, const half_t* __restrict__ b_e0w2,
    half_t* __restrict__ g_lat0, float* __restrict__ g_fs, float* __restrict__ g_fv,
    float* __restrict__ raw0, int E) {
    const int lane = threadIdx.x & 63, nl = lane & 31, q = lane >> 5;
    const int g = blockIdx.x * 2 + (threadIdx.x >> 6);
    const int e = g * 32 + nl;
    int ce = g_eidx[e];
    float4 ea = *reinterpret_cast<const float4*>(g_ea + e * 4);
    float cut = poly_cut(g_eu[e]);

    float xw[4];
    if (q == 0) {
        int ne = g_eidx[E + e];
        float4 nc = *reinterpret_cast<const float4*>(g_na + ce * 4);
        float4 nn = *reinterpret_cast<const float4*>(g_na + ne * 4);
        xw[0] = pkh(nc.x, nc.y); xw[1] = pkh(nc.z, nc.w);
        xw[2] = pkh(nn.x, nn.y); xw[3] = pkh(nn.z, nn.w);
    } else {
        f32x4 m0 = ntl_f4(g_emb + e * 8);
        f32x4 m1 = ntl_f4(g_emb + e * 8 + 4);
        xw[0] = pkh(m0[0], m0[1]); xw[1] = pkh(m0[2], m0[3]);
        xw[2] = pkh(m1[0], m1[1]); xw[3] = pkh(m1[2], m1[3]);
    }

    float hB[32], lB[32];
#pragma unroll
    for (int c = 0; c < 4; ++c) {  // w2b1: K=16
        f32x16 d = colstage<2>(b_w2b1, xw, c, nl, q);
        silu16(d);
        d2b(d, lane, q, &hB[8 * c], &hB[8 * c + 4]);
    }
    half_t* gl = g_lat0 + (size_t)g * 4096;
#pragma unroll
    for (int c = 0; c < 4; ++c) {  // w2b2 -> lat = cut*D
        f32x16 d = colstage<16>(b_w2b2, hB, c, nl, q);
#pragma unroll
        for (int i = 0; i < 16; ++i) d[i] *= cut;
        d2b(d, lane, q, &lB[8 * c], &lB[8 * c + 4]);
        nts_h8(mk8(&lB[8 * c]), gl + ((4 * c + q) * 32 + nl) * 8);
        nts_h8(mk8(&lB[8 * c + 4]), gl + ((4 * c + 2 + q) * 32 + nl) * 8);
    }
#pragma unroll
    for (int c = 0; c < 4; ++c) {  // e0w1
        f32x16 d = colstage<16>(b_e0w1, lB, c, nl, q);
        silu16(d);
        d2b(d, lane, q, &hB[8 * c], &hB[8 * c + 4]);
    }
    {  // e0w2 both mtiles interleaved
        f32x16 d0 = colstage<16>(b_e0w2, hB, 0, nl, q);
        f32x16 d1 = colstage<16>(b_e0w2, hB, 1, nl, q);
#pragma unroll
        for (int r = 0; r < 16; ++r) {
            int f = (r & 3) + 8 * (r >> 2) + 4 * q;
            int u = f >> 1;
            float v0 = d0[r], v1 = d1[r];
            if ((f & 1) == 0) {
                nts_f(v0 * ea.x, g_fs + e * 16 + u);
                atomicAdd(&raw0[ce * 64 + u], v1 * ea.x);
            } else {
                nts_f(v0 * ea.y, g_fv + e * 48 + u * 3 + 0);
                nts_f(v0 * ea.z, g_fv + e * 48 + u * 3 + 1);
                nts_f(v0 * ea.w, g_fv + e * 48 + u * 3 + 2);
                atomicAdd(&raw0[ce * 64 + 16 + u * 3 + 0], v1 * ea.y);
                atomicAdd(&raw0[ce * 64 + 16 + u * 3 + 1], v1 * ea.z);
                atomicAdd(&raw0[ce * 64 + 16 + u * 3 + 2], v1 * ea.w);
            }
        }
    }
}

// =====================================================================
// K2: per-node env linear (f32).
// =====================================================================
__global__ __launch_bounds__(256) void k_node_lin(
    const float* __restrict__ raw, const float* __restrict__ wls,
    const float* __restrict__ wlv, float* __restrict__ ls, float* __restrict__ lv,
    int Nn) {
    int gid = blockIdx.x * 256 + threadIdx.x;
    if (gid >= Nn * 16) return;
    int n = gid >> 4, v = gid & 15;
    float as = 0.f, a0 = 0.f, a1 = 0.f, a2 = 0.f;
    const float* rp = raw + n * 64;
#pragma unroll
    for (int u = 0; u < 16; ++u) {
        float w1 = wls[u * 16 + v];
        float w2 = wlv[u * 16 + v];
        as = fmaf(rp[u], w1, as);
        a0 = fmaf(rp[16 + u * 3 + 0], w2, a0);
        a1 = fmaf(rp[16 + u * 3 + 1], w2, a1);
        a2 = fmaf(rp[16 + u * 3 + 2], w2, a2);
    }
    ls[n * 16 + v] = as * SC_ENV;
    lv[n * 48 + v * 3 + 0] = a0 * SC_ENV;
    lv[n * 48 + v * 3 + 1] = a1 * SC_ENV;
    lv[n * 48 + v * 3 + 2] = a2 * SC_ENV;
}

// =====================================================================
// K3: layer0 role-split. blockIdx&1==0: fold (gw1+gw2 -> gfs2/gfv2).
//                        blockIdx&1==1: latent (lat1/e1 -> lat1, raw1).
// One wave per block; independent pipelines; NT streaming.
// =====================================================================
__global__ __launch_bounds__(64, 3) void k_layer0(
    const float* __restrict__ g_ea, const float* __restrict__ g_eu,
    const int* __restrict__ g_eidx,
    const float* __restrict__ g_fs, const float* __restrict__ g_fv,
    float* __restrict__ gfs2, float* __restrict__ gfv2,
    const float* __restrict__ ls0, const float* __restrict__ lv0,
    const half_t* __restrict__ b_lat1w1, const half_t* __restrict__ b_lat1w2,
    const half_t* __restrict__ b_e1w1, const half_t* __restrict__ b_e1w2,
    const half_t* __restrict__ b_gw1, const half_t* __restrict__ b_gw2,
    const half_t* __restrict__ g_lat0, half_t* __restrict__ g_lat1,
    float* __restrict__ raw1, int E) {
    __shared__ half_t sS[32 * SSD];
    __shared__ half_t Vsh[32 * VPH];
    const int lane = threadIdx.x, nl = lane & 31, q = lane >> 5;
    const int bid = blockIdx.x, g = bid >> 1, role = bid & 1;
    const int e = g * 32 + nl;
    int ce = g_eidx[e];

    float lB[40];
    const half_t* gl0 = g_lat0 + (size_t)g * 4096;
#pragma unroll
    for (int h = 0; h < 8; ++h) {
        f32x4 v = ntl_f4(gl0 + ((2 * h + q) * 32 + nl) * 8);
        lB[h * 4 + 0] = v[0]; lB[h * 4 + 1] = v[1];
        lB[h * 4 + 2] = v[2]; lB[h * 4 + 3] = v[3];
    }
    // gather env0: lane handles its edge, m = 8q..8q+7
#pragma unroll
    for (int mm = 0; mm < 8; ++mm) {
        int m = q * 8 + mm;
        float fs = ntl_f(g_fs + e * 16 + m);
        float fv0 = ntl_f(g_fv + e * 48 + m * 3 + 0);
        float fv1 = ntl_f(g_fv + e * 48 + m * 3 + 1);
        float fv2 = ntl_f(g_fv + e * 48 + m * 3 + 2);
        float es = ls0[ce * 16 + m];
        float ev0 = lv0[ce * 48 + m * 3 + 0];
        float ev1 = lv0[ce * 48 + m * 3 + 1];
        float ev2 = lv0[ce * 48 + m * 3 + 2];
        float s1 = fs * es;
        float s2 = (fv0 * ev0 + fv1 * ev1 + fv2 * ev2) * INV_S3;
        sS[nl * SSD + 2 * m + 0] = (half_t)s1;
        sS[nl * SSD + 2 * m + 1] = (half_t)s2;
        if (role == 0) {
            half_t* vp = Vsh + nl * VPH;
            vp[m * 3 + 0] = (half_t)(fs * ev0);
            vp[m * 3 + 1] = (half_t)(fs * ev1);
            vp[m * 3 + 2] = (half_t)(fs * ev2);
            vp[(16 + m) * 3 + 0] = (half_t)(fv0 * es);
            vp[(16 + m) * 3 + 1] = (half_t)(fv1 * es);
            vp[(16 + m) * 3 + 2] = (half_t)(fv2 * es);
            vp[(32 + m) * 3 + 0] = (half_t)((fv1 * ev2 - fv2 * ev1) * INV_S2);
            vp[(32 + m) * 3 + 1] = (half_t)((fv2 * ev0 - fv0 * ev2) * INV_S2);
            vp[(32 + m) * 3 + 2] = (half_t)((fv0 * ev1 - fv1 * ev0) * INV_S2);
        }
    }
    __syncthreads();

    // latent windows 8,9 (scalars)
#pragma unroll
    for (int j2 = 0; j2 < 4; ++j2) {
        lB[32 + j2] = ld_pk2(sS + nl * SSD + 8 * q + 2 * j2);
        lB[36 + j2] = ld_pk2(sS + nl * SSD + 16 + 8 * q + 2 * j2);
    }

    float hB[32];
    if (role == 0) {
        // ---- fold role ----
#pragma unroll
        for (int c = 0; c < 4; ++c) {  // gw1
            f32x16 d = colstage<20>(b_gw1, lB, c, nl, q);
            silu16(d);
            d2b(d, lane, q, &hB[8 * c], &hB[8 * c + 4]);
        }
        {  // ws fold: mtiles 0..15, unroll-2
            float fsacc[8];
#pragma unroll
            for (int s = 0; s < 8; ++s) fsacc[s] = 0.f;
            for (int c = 0; c < 16; c += 2) {
                f32x16 d0 = colstage<16>(b_gw2, hB, c, nl, q);
                f32x16 d1 = colstage<16>(b_gw2, hB, c + 1, nl, q);
#pragma unroll
                for (int cc = 0; cc < 2; ++cc) {
                    const f32x16& d = cc ? d1 : d0;
                    int pu0 = 2 * (c + cc), pu1 = pu0 + 1;
                    float S0 = (float)sS[nl * SSD + 2 * (pu0 & 15) + (pu0 >> 4)];
                    float S1 = (float)sS[nl * SSD + 2 * (pu1 & 15) + (pu1 >> 4)];
#pragma unroll
                    for (int r = 0; r < 16; ++r) {
                        int a = r >> 2, bb = r & 3, slot = (a & 1) * 4 + bb;
                        fsacc[slot] = fmaf((a < 2) ? S0 : S1, d[r], fsacc[slot]);
                    }
                }
            }
#pragma unroll
            for (int s = 0; s < 8; ++s) {
                int v = (s & 3) + 4 * q + 8 * (s >> 2);
                nts_f(fsacc[s] * SC_FS, gfs2 + e * 16 + v);
            }
        }
        {  // wv fold: mtiles 16..39, unroll-2
            float fvacc[8][3];
#pragma unroll
            for (int s = 0; s < 8; ++s) fvacc[s][0] = fvacc[s][1] = fvacc[s][2] = 0.f;
            for (int c = 16; c < 40; c += 2) {
                f32x16 d0 = colstage<16>(b_gw2, hB, c, nl, q);
                f32x16 d1 = colstage<16>(b_gw2, hB, c + 1, nl, q);
#pragma unroll
                for (int cc = 0; cc < 2; ++cc) {
                    const f32x16& d = cc ? d1 : d0;
                    int w0 = 2 * (c + cc) - 32, w1 = w0 + 1;
                    const half_t* vp = Vsh + nl * VPH;
                    float V00 = (float)vp[w0 * 3], V01 = (float)vp[w0 * 3 + 1], V02 = (float)vp[w0 * 3 + 2];
                    float V10 = (float)vp[w1 * 3], V11 = (float)vp[w1 * 3 + 1], V12 = (float)vp[w1 * 3 + 2];
#pragma unroll
                    for (int r = 0; r < 16; ++r) {
                        int a = r >> 2, bb = r & 3, slot = (a & 1) * 4 + bb;
                        float x0 = (a < 2) ? V00 : V10;
                        float x1 = (a < 2) ? V01 : V11;
                        float x2 = (a < 2) ? V02 : V12;
                        fvacc[slot][0] = fmaf(x0, d[r], fvacc[slot][0]);
                        fvacc[slot][1] = fmaf(x1, d[r], fvacc[slot][1]);
                        fvacc[slot][2] = fmaf(x2, d[r], fvacc[slot][2]);
                    }
                }
            }
#pragma unroll
            for (int s = 0; s < 8; ++s) {
                int v = (s & 3) + 4 * q + 8 * (s >> 2);
                nts_f(fvacc[s][0] * SC_FV, gfv2 + e * 48 + v * 3 + 0);
                nts_f(fvacc[s][1] * SC_FV, gfv2 + e * 48 + v * 3 + 1);
                nts_f(fvacc[s][2] * SC_FV, gfv2 + e * 48 + v * 3 + 2);
            }
        }
    } else {
        // ---- latent role ----
        float4 ea = *reinterpret_cast<const float4*>(g_ea + e * 4);
        float cut = poly_cut(g_eu[e]);
#pragma unroll
        for (int c = 0; c < 4; ++c) {  // lat1w1
            f32x16 d = colstage<20>(b_lat1w1, lB, c, nl, q);
            silu16(d);
            d2b(d, lane, q, &hB[8 * c], &hB[8 * c + 4]);
        }
        half_t* gl1 = g_lat1 + (size_t)g * 4096;
        float sc = A_COLD * cut;
#pragma unroll
        for (int c = 0; c < 4; ++c) {  // lat1w2 + combine -> lat'
            f32x16 d = colstage<16>(b_lat1w2, hB, c, nl, q);
#pragma unroll
            for (int i = 0; i < 16; ++i) d[i] *= sc;
            float nw[8];
            d2b(d, lane, q, nw, nw + 4);
#pragma unroll
            for (int p = 0; p < 8; ++p) {
                float2 o = uph(lB[8 * c + p]);
                float2 nn2 = uph(nw[p]);
                lB[8 * c + p] = pkh(C_OLD * o.x + nn2.x, C_OLD * o.y + nn2.y);
            }
            nts_h8(mk8(&lB[8 * c]), gl1 + ((4 * c + q) * 32 + nl) * 8);
            nts_h8(mk8(&lB[8 * c + 4]), gl1 + ((4 * c + 2 + q) * 32 + nl) * 8);
        }
#pragma unroll
        for (int c = 0; c < 4; ++c) {  // e1w1 (K=128, lat' windows 0..7)
            f32x16 d = colstage<16>(b_e1w1, lB, c, nl, q);
            silu16(d);
            d2b(d, lane, q, &hB[8 * c], &hB[8 * c + 4]);
        }
        {  // e1w2 -> raw1 scatter
            f32x16 d = colstage<16>(b_e1w2, hB, 0, nl, q);
#pragma unroll
            for (int r = 0; r < 16; ++r) {
                int f = (r & 3) + 8 * (r >> 2) + 4 * q;
                int u = f >> 1;
                float val = d[r];
                if ((f & 1) == 0) {
                    atomicAdd(&raw1[ce * 64 + u], val * ea.x);
                } else {
                    atomicAdd(&raw1[ce * 64 + 16 + u * 3 + 0], val * ea.y);
                    atomicAdd(&raw1[ce * 64 + 16 + u * 3 + 1], val * ea.z);
                    atomicAdd(&raw1[ce * 64 + 16 + u * 3 + 2], val * ea.w);
                }
            }
        }
    }
}

// =====================================================================
// K5: layer1 split over fold-mtile halves. Each block: gather + flw + gw1 +
// 12 fold mtiles; partial output via atomicAdd into zeroed g_out.
// =====================================================================
__global__ __launch_bounds__(64, 3) void k_layer1(
    const int* __restrict__ g_eidx, const float* __restrict__ gfs2,
    const float* __restrict__ gfv2, const float* __restrict__ ls1,
    const float* __restrict__ lv1,
    const half_t* __restrict__ b_flw1, const half_t* __restrict__ b_flw2,
    const half_t* __restrict__ b_gw1, const half_t* __restrict__ b_gw2,
    const half_t* __restrict__ g_lat1, float* __restrict__ g_out, int E) {
    __shared__ half_t sS[32 * SSD];
    __shared__ half_t Vsh[32 * VPH];
    const int lane = threadIdx.x, nl = lane & 31, q = lane >> 5;
    const int bid = blockIdx.x, g = bid >> 1, hf = bid & 1;
    const int e = g * 32 + nl;
    int ce = g_eidx[e];

    float lB[40];
    const half_t* gl1 = g_lat1 + (size_t)g * 4096;
#pragma unroll
    for (int h = 0; h < 8; ++h) {
        f32x4 v = ntl_f4(gl1 + ((2 * h + q) * 32 + nl) * 8);
        lB[h * 4 + 0] = v[0]; lB[h * 4 + 1] = v[1];
        lB[h * 4 + 2] = v[2]; lB[h * 4 + 3] = v[3];
    }
#pragma unroll
    for (int mm = 0; mm < 8; ++mm) {
        int m = q * 8 + mm;
        float fs = ntl_f(gfs2 + e * 16 + m);
        float fv0 = ntl_f(gfv2 + e * 48 + m * 3 + 0);
        float fv1 = ntl_f(gfv2 + e * 48 + m * 3 + 1);
        float fv2 = ntl_f(gfv2 + e * 48 + m * 3 + 2);
        float es = ls1[ce * 16 + m];
        float ev0 = lv1[ce * 48 + m * 3 + 0];
        float ev1 = lv1[ce * 48 + m * 3 + 1];
        float ev2 = lv1[ce * 48 + m * 3 + 2];
        float s1 = fs * es;
        float s2 = (fv0 * ev0 + fv1 * ev1 + fv2 * ev2) * INV_S3;
        sS[nl * SSD + 2 * m + 0] = (half_t)s1;
        sS[nl * SSD + 2 * m + 1] = (half_t)s2;
        half_t* vp = Vsh + nl * VPH;
        vp[m * 3 + 0] = (half_t)(fs * ev0);
        vp[m * 3 + 1] = (half_t)(fs * ev1);
        vp[m * 3 + 2] = (half_t)(fs * ev2);
        vp[(16 + m) * 3 + 0] = (half_t)(fv0 * es);
        vp[(16 + m) * 3 + 1] = (half_t)(fv1 * es);
        vp[(16 + m) * 3 + 2] = (half_t)(fv2 * es);
        vp[(32 + m) * 3 + 0] = (half_t)((fv1 * ev2 - fv2 * ev1) * INV_S2);
        vp[(32 + m) * 3 + 1] = (half_t)((fv2 * ev0 - fv0 * ev2) * INV_S2);
        vp[(32 + m) * 3 + 2] = (half_t)((fv0 * ev1 - fv1 * ev0) * INV_S2);
    }
    __syncthreads();

#pragma unroll
    for (int j2 = 0; j2 < 4; ++j2) {
        lB[32 + j2] = ld_pk2(sS + nl * SSD + 8 * q + 2 * j2);
        lB[36 + j2] = ld_pk2(sS + nl * SSD + 16 + 8 * q + 2 * j2);
    }

    float hB[32];
#pragma unroll
    for (int c = 0; c < 4; ++c) {  // flw1
        f32x16 d = colstage<20>(b_flw1, lB, c, nl, q);
        silu16(d);
        d2b(d, lane, q, &hB[8 * c], &hB[8 * c + 4]);
    }
    float fw[8];
    {  // flw2 (N=16)
        f32x16 d = colstage<16>(b_flw2, hB, 0, nl, q);
#pragma unroll
        for (int r = 0; r < 8; ++r) fw[r] = d[r];
    }
#pragma unroll
    for (int c = 0; c < 4; ++c) {  // gw1
        f32x16 d = colstage<20>(b_gw1, lB, c, nl, q);
        silu16(d);
        d2b(d, lane, q, &hB[8 * c], &hB[8 * c + 4]);
    }
    {  // gw2 wv fold: this block's 12 mtiles
        float fvacc[8][3];
#pragma unroll
        for (int s = 0; s < 8; ++s) fvacc[s][0] = fvacc[s][1] = fvacc[s][2] = 0.f;
        int c0 = 16 + 12 * hf;
        for (int c = c0; c < c0 + 12; c += 2) {
            f32x16 d0 = colstage<16>(b_gw2, hB, c, nl, q);
            f32x16 d1 = colstage<16>(b_gw2, hB, c + 1, nl, q);
#pragma unroll
            for (int cc = 0; cc < 2; ++cc) {
                const f32x16& d = cc ? d1 : d0;
                int w0 = 2 * (c + cc) - 32, w1 = w0 + 1;
                const half_t* vp = Vsh + nl * VPH;
                float V00 = (float)vp[w0 * 3], V01 = (float)vp[w0 * 3 + 1], V02 = (float)vp[w0 * 3 + 2];
                float V10 = (float)vp[w1 * 3], V11 = (float)vp[w1 * 3 + 1], V12 = (float)vp[w1 * 3 + 2];
#pragma unroll
                for (int r = 0; r < 16; ++r) {
                    int a = r >> 2, bb = r & 3, slot = (a & 1) * 4 + bb;
                    float x0 = (a < 2) ? V00 : V10;
                    float x1 = (a < 2) ? V01 : V11;
                    float x2 = (a < 2) ? V02 : V12;
                    fvacc[slot][0] = fmaf(x0, d[r], fvacc[slot][0]);
                    fvacc[slot][1] = fmaf(x1, d[r], fvacc[slot][1]);
                    fvacc[slot][2] = fmaf(x2, d[r], fvacc[slot][2]);
                }
            }
        }
        float o0 = 0.f, o1 = 0.f, o2 = 0.f;
#pragma unroll
        for (int s = 0; s < 8; ++s) {
            o0 = fmaf(fw[s], fvacc[s][0], o0);
            o1 = fmaf(fw[s], fvacc[s][1], o1);
            o2 = fmaf(fw[s], fvacc[s][2], o2);
        }
        o0 += __shfl(o0, lane ^ 32, 64);
        o1 += __shfl(o1, lane ^ 32, 64);
        o2 += __shfl(o2, lane ^ 32, 64);
        if (q == 0) {
            atomicAdd(&g_out[e * 3 + 0], o0 * SC_OUT);
            atomicAdd(&g_out[e * 3 + 1], o1 * SC_OUT);
            atomicAdd(&g_out[e * 3 + 2], o2 * SC_OUT);
        }
    }
}

// =====================================================================
extern "C" void kernel_launch(void* const* d_in, const int* in_sizes, int n_in,
                              void* d_out, int out_size, void* d_ws, size_t ws_size,
                              hipStream_t stream) {
    const float* g_ea = (const float*)d_in[0];
    const float* g_na = (const float*)d_in[1];
    const float* g_emb = (const float*)d_in[2];
    const float* g_eu = (const float*)d_in[3];
    const int* g_eidx = (const int*)d_in[4];
    const float* w2b1 = (const float*)d_in[5];
    const float* w2b2 = (const float*)d_in[6];
    const float* lat1w1 = (const float*)d_in[7];
    const float* lat1w2 = (const float*)d_in[8];
    const float* e0w1 = (const float*)d_in[9];
    const float* e0w2 = (const float*)d_in[10];
    const float* e1w1 = (const float*)d_in[11];
    const float* e1w2 = (const float*)d_in[12];
    const float* l2w0w1 = (const float*)d_in[13];
    const float* l2w0w2 = (const float*)d_in[14];
    const float* l2w1w1 = (const float*)d_in[15];
    const float* l2w1w2 = (const float*)d_in[16];
    const float* envws = (const float*)d_in[17];
    const float* envwv = (const float*)d_in[18];
    const float* flw1 = (const float*)d_in[19];
    const float* flw2 = (const float*)d_in[20];
    float* out = (float*)d_out;

    const int E = in_sizes[3];       // 120000
    const int Nn = in_sizes[1] / 4;  // 5000
    const int nblk = E / 32;         // 3750
    const int nblk2 = nblk / 2;      // 1875

    float* p = (float*)d_ws;
    float* gfs = p;  p += (size_t)E * 16;
    float* gfv = p;  p += (size_t)E * 48;
    float* gfs2 = p; p += (size_t)E * 16;
    float* gfv2 = p; p += (size_t)E * 48;
    float* raw0 = p; p += (size_t)Nn * 64;
    float* raw1 = p; p += (size_t)Nn * 64;
    float* ls0 = p;  p += (size_t)Nn * 16;
    float* lv0 = p;  p += (size_t)Nn * 48;
    float* ls1 = p;  p += (size_t)Nn * 16;
    float* lv1 = p;  p += (size_t)Nn * 48;
    half_t* hp = (half_t*)p;
    half_t* lat0h = hp; hp += (size_t)nblk * 4096;
    half_t* lat1h = hp; hp += (size_t)nblk * 4096;

    const int KN[14][2] = {{16, 128}, {128, 128}, {128, 128}, {128, 64},
                           {160, 128}, {128, 128}, {128, 128}, {128, 32},
                           {160, 128}, {128, 1280}, {160, 128}, {128, 1280},
                           {160, 128}, {128, 16}};
    const float* srcs[14] = {w2b1, w2b2, e0w1, e0w2, lat1w1, lat1w2, e1w1, e1w2,
                             l2w0w1, l2w0w2, l2w1w1, l2w1w2, flw1, flw2};
    PackArgs pa;
    half_t* bptr[14];
    for (int i = 0; i < 14; ++i) {
        int K = KN[i][0], N = KN[i][1];
        int Npad = (N + 31) & ~31;
        bptr[i] = hp;
        hp += (size_t)K * Npad;
        pa.src[i] = srcs[i];
        pa.dst[i] = bptr[i];
        pa.K[i] = K;
        pa.N[i] = N;
    }

    k_pack<<<dim3(80, 14), 256, 0, stream>>>(pa);

    const int nzero = Nn * 128;  // raw0 + raw1 contiguous
    k_zero<<<(nzero + 255) / 256, 256, 0, stream>>>(raw0, nzero);
    k_zero<<<(out_size + 255) / 256, 256, 0, stream>>>(out, out_size);

    const int nb2 = (Nn * 16 + 255) / 256;

    k_edge_front<<<nblk2, 128, 0, stream>>>(g_ea, g_na, g_emb, g_eu, g_eidx,
                                            bptr[0], bptr[1], bptr[2], bptr[3],
                                            lat0h, gfs, gfv, raw0, E);
    k_node_lin<<<nb2, 256, 0, stream>>>(raw0, envws, envwv, ls0, lv0, Nn);
    k_layer0<<<nblk * 2, 64, 0, stream>>>(g_ea, g_eu, g_eidx, gfs, gfv, gfs2, gfv2,
                                          ls0, lv0, bptr[4], bptr[5], bptr[6],
                                          bptr[7], bptr[8], bptr[9], lat0h, lat1h,
                                          raw1, E);
    k_node_lin<<<nb2, 256, 0, stream>>>(raw1, envws + 256, envwv + 256, ls1, lv1, Nn);
    k_layer1<<<nblk * 2, 64, 0, stream>>>(g_eidx, gfs2, gfv2, ls1, lv1,
                                          bptr[12], bptr[13], bptr[10], bptr[11],
                                          lat1h, out, E);
}

// Round 11
// 838.897 us; speedup vs baseline: 1.0856x; 1.0856x over previous
//
#include <hip/hip_runtime.h>

typedef _Float16 half_t;
typedef _Float16 half8 __attribute__((ext_vector_type(8)));
typedef _Float16 half2_t __attribute__((ext_vector_type(2)));
typedef float f32x16 __attribute__((ext_vector_type(16)));
typedef float f32x4 __attribute__((ext_vector_type(4)));

#define DEVINL __device__ __forceinline__

// ---------- constants ----------
#define INV_S3 0.57735026918962576f   // 1/sqrt(3)
#define INV_S2 0.70710678118654752f   // 1/sqrt(2)
#define C_OLD  0.89442719099991588f   // 1/sqrt(1.25)
#define A_COLD 0.44721359549995794f   // 0.5/sqrt(1.25)
#define SC_ENV 0.05590169943749474f   // (1/sqrt(20)) * (1/4)
#define SC_FS  0.17677669529663688f   // 1/sqrt(32)
#define SC_FV  0.14433756729740643f   // 1/sqrt(48)
#define SC_OUT 0.03608439182435161f   // (1/4)/sqrt(48) — includes layer-1 fold scale
#define SSD 34                         // sS stride (halfs)
#define VPH 146                        // V stride (halfs)

DEVINL float silu_f(float x) { return x / (1.f + __expf(-x)); }

DEVINL float poly_cut(float u) {
    float u2 = u * u, u4 = u2 * u2, u6 = u4 * u2;
    float f = 1.f - 28.f * u6 + 48.f * u6 * u - 21.f * u6 * u2;
    return (u < 1.f) ? f : 0.f;
}

DEVINL float pkh(float a, float b) {
    half2_t h; h[0] = (half_t)a; h[1] = (half_t)b;
    return __builtin_bit_cast(float, h);
}
DEVINL float2 uph(float p) {
    half2_t h = __builtin_bit_cast(half2_t, p);
    return make_float2((float)h[0], (float)h[1]);
}
DEVINL half8 mk8(const float* w) {
    f32x4 v = {w[0], w[1], w[2], w[3]};
    return __builtin_bit_cast(half8, v);
}
DEVINL float ld_pk2(const half_t* p) {
    half2_t h; h[0] = p[0]; h[1] = p[1];
    return __builtin_bit_cast(float, h);
}
// ---- non-temporal streaming access (keep weights resident in cache) ----
DEVINL float ntl_f(const float* p) { return __builtin_nontemporal_load(p); }
DEVINL void nts_f(float v, float* p) { __builtin_nontemporal_store(v, p); }
DEVINL f32x4 ntl_f4(const void* p) {
    return __builtin_nontemporal_load((const f32x4*)p);
}
DEVINL void nts_h8(half8 v, half_t* p) {
    __builtin_nontemporal_store(v, (half8*)p);
}

// =====================================================================
// Edge-column MFMA stage: A = weights [M=features], B = edges (in regs).
// Weight pack: cell(mtile,kblk,m) at halfs[((mtile*KB+kblk)*32+m)*8+j]
// D: lane owns edge col n = lane&31; row f = (r&3) + 8*(r>>2) + 4*(lane>>5).
// =====================================================================
template <int KB>  // K/8
DEVINL f32x16 colstage(const half_t* __restrict__ Wg, const float* B, int mtile,
                       int nl, int q) {
    const half_t* ap = Wg + (((size_t)mtile * KB + q) * 32 + nl) * 8;
    f32x16 acc;
#pragma unroll
    for (int i = 0; i < 16; ++i) acc[i] = 0.f;
#pragma unroll
    for (int h = 0; h < KB / 2; ++h) {
        half8 a = *reinterpret_cast<const half8*>(ap + h * 512);
        acc = __builtin_amdgcn_mfma_f32_32x32x16_f16(a, mk8(B + h * 4), acc, 0, 0, 0);
    }
    return acc;
}

// ---- explicit register prefetch pipeline for K=128 fold stages ----
struct WFrag { half8 a[8]; };

DEVINL WFrag ldw16(const half_t* __restrict__ Wg, int mtile, int nl, int q) {
    const half_t* ap = Wg + (((size_t)mtile * 16 + q) * 32 + nl) * 8;
    WFrag f;
#pragma unroll
    for (int h = 0; h < 8; ++h)
        f.a[h] = *reinterpret_cast<const half8*>(ap + h * 512);
    return f;
}

DEVINL f32x16 mfma8w(const WFrag& f, const float* B) {
    f32x16 acc;
#pragma unroll
    for (int i = 0; i < 16; ++i) acc[i] = 0.f;
#pragma unroll
    for (int h = 0; h < 8; ++h)
        acc = __builtin_amdgcn_mfma_f32_32x32x16_f16(f.a[h], mk8(B + h * 4), acc, 0, 0, 0);
    return acc;
}

DEVINL void silu16(f32x16& a) {
#pragma unroll
    for (int i = 0; i < 16; ++i) a[i] = silu_f(a[i]);
}

// D (f32 regs) -> B-frag for next stage: two k-windows of 4 packed floats.
DEVINL void d2b(const f32x16& d, int lane, int q, float* wA, float* wB) {
    float pk[8];
#pragma unroll
    for (int a2 = 0; a2 < 4; ++a2) {
        pk[a2 * 2 + 0] = pkh(d[4 * a2 + 0], d[4 * a2 + 1]);
        pk[a2 * 2 + 1] = pkh(d[4 * a2 + 2], d[4 * a2 + 3]);
    }
#pragma unroll
    for (int t = 0; t < 2; ++t) {
        float k0 = q ? pk[(2 * t + 1) * 2 + 0] : pk[(2 * t) * 2 + 0];
        float k1 = q ? pk[(2 * t + 1) * 2 + 1] : pk[(2 * t) * 2 + 1];
        float s0 = q ? pk[(2 * t) * 2 + 0] : pk[(2 * t + 1) * 2 + 0];
        float s1 = q ? pk[(2 * t) * 2 + 1] : pk[(2 * t + 1) * 2 + 1];
        float r0 = __shfl(s0, lane ^ 32, 64);
        float r1 = __shfl(s1, lane ^ 32, 64);
        float* w = t ? wB : wA;
        w[0] = q ? r0 : k0;
        w[1] = q ? r1 : k1;
        w[2] = q ? k0 : r0;
        w[3] = q ? k1 : r1;
    }
}

// =====================================================================
__global__ __launch_bounds__(256) void k_zero(float* __restrict__ p, int n) {
    int i = blockIdx.x * 256 + threadIdx.x;
    if (i < n) p[i] = 0.f;
}

// =====================================================================
struct PackArgs {
    const float* src[14];
    half_t* dst[14];
    int K[14];
    int N[14];
};

__global__ __launch_bounds__(256) void k_pack(PackArgs pa) {
    int mi = blockIdx.y;
    int K = pa.K[mi], N = pa.N[mi];
    int Npad = (N + 31) & ~31;
    int KB = K >> 3;
    int cells = KB * Npad;
    int cell = blockIdx.x * 256 + threadIdx.x;
    if (cell >= cells) return;
    int nn = cell & 31, r2 = cell >> 5;
    int kblk = r2 % KB, ntile = r2 / KB;
    int n = ntile * 32 + nn;
    const float* W = pa.src[mi];
    half8 v;
#pragma unroll
    for (int j = 0; j < 8; ++j) {
        int k = kblk * 8 + j;
        v[j] = (half_t)((n < N) ? W[k * N + n] : 0.f);
    }
    *reinterpret_cast<half8*>(pa.dst[mi] + (size_t)cell * 8) = v;
}

// =====================================================================
// K1: front. 2 independent waves/block, 32 edges each, no LDS.
// =====================================================================
__global__ __launch_bounds__(128, 4) void k_edge_front(
    const float* __restrict__ g_ea, const float* __restrict__ g_na,
    const float* __restrict__ g_emb, const float* __restrict__ g_eu,
    const int* __restrict__ g_eidx,
    const half_t* __restrict__ b_w2b1, const half_t* __restrict__ b_w2b2,
    const half_t* __restrict__ b_e0w1, const half_t* __restrict__ b_e0w2,
    half_t* __restrict__ g_lat0, float* __restrict__ g_fs, float* __restrict__ g_fv,
    float* __restrict__ raw0, int E) {
    const int lane = threadIdx.x & 63, nl = lane & 31, q = lane >> 5;
    const int g = blockIdx.x * 2 + (threadIdx.x >> 6);
    const int e = g * 32 + nl;
    int ce = g_eidx[e];
    float4 ea = *reinterpret_cast<const float4*>(g_ea + e * 4);
    float cut = poly_cut(g_eu[e]);

    float xw[4];
    if (q == 0) {
        int ne = g_eidx[E + e];
        float4 nc = *reinterpret_cast<const float4*>(g_na + ce * 4);
        float4 nn = *reinterpret_cast<const float4*>(g_na + ne * 4);
        xw[0] = pkh(nc.x, nc.y); xw[1] = pkh(nc.z, nc.w);
        xw[2] = pkh(nn.x, nn.y); xw[3] = pkh(nn.z, nn.w);
    } else {
        f32x4 m0 = ntl_f4(g_emb + e * 8);
        f32x4 m1 = ntl_f4(g_emb + e * 8 + 4);
        xw[0] = pkh(m0[0], m0[1]); xw[1] = pkh(m0[2], m0[3]);
        xw[2] = pkh(m1[0], m1[1]); xw[3] = pkh(m1[2], m1[3]);
    }

    float hB[32], lB[32];
#pragma unroll
    for (int c = 0; c < 4; ++c) {  // w2b1: K=16
        f32x16 d = colstage<2>(b_w2b1, xw, c, nl, q);
        silu16(d);
        d2b(d, lane, q, &hB[8 * c], &hB[8 * c + 4]);
    }
    half_t* gl = g_lat0 + (size_t)g * 4096;
#pragma unroll
    for (int c = 0; c < 4; ++c) {  // w2b2 -> lat = cut*D
        f32x16 d = colstage<16>(b_w2b2, hB, c, nl, q);
#pragma unroll
        for (int i = 0; i < 16; ++i) d[i] *= cut;
        d2b(d, lane, q, &lB[8 * c], &lB[8 * c + 4]);
        nts_h8(mk8(&lB[8 * c]), gl + ((4 * c + q) * 32 + nl) * 8);
        nts_h8(mk8(&lB[8 * c + 4]), gl + ((4 * c + 2 + q) * 32 + nl) * 8);
    }
#pragma unroll
    for (int c = 0; c < 4; ++c) {  // e0w1
        f32x16 d = colstage<16>(b_e0w1, lB, c, nl, q);
        silu16(d);
        d2b(d, lane, q, &hB[8 * c], &hB[8 * c + 4]);
    }
    {  // e0w2 both mtiles interleaved
        f32x16 d0 = colstage<16>(b_e0w2, hB, 0, nl, q);
        f32x16 d1 = colstage<16>(b_e0w2, hB, 1, nl, q);
#pragma unroll
        for (int r = 0; r < 16; ++r) {
            int f = (r & 3) + 8 * (r >> 2) + 4 * q;
            int u = f >> 1;
            float v0 = d0[r], v1 = d1[r];
            if ((f & 1) == 0) {
                nts_f(v0 * ea.x, g_fs + e * 16 + u);
                atomicAdd(&raw0[ce * 64 + u], v1 * ea.x);
            } else {
                nts_f(v0 * ea.y, g_fv + e * 48 + u * 3 + 0);
                nts_f(v0 * ea.z, g_fv + e * 48 + u * 3 + 1);
                nts_f(v0 * ea.w, g_fv + e * 48 + u * 3 + 2);
                atomicAdd(&raw0[ce * 64 + 16 + u * 3 + 0], v1 * ea.y);
                atomicAdd(&raw0[ce * 64 + 16 + u * 3 + 1], v1 * ea.z);
                atomicAdd(&raw0[ce * 64 + 16 + u * 3 + 2], v1 * ea.w);
            }
        }
    }
}

// =====================================================================
// K2: per-node env linear (f32).
// =====================================================================
__global__ __launch_bounds__(256) void k_node_lin(
    const float* __restrict__ raw, const float* __restrict__ wls,
    const float* __restrict__ wlv, float* __restrict__ ls, float* __restrict__ lv,
    int Nn) {
    int gid = blockIdx.x * 256 + threadIdx.x;
    if (gid >= Nn * 16) return;
    int n = gid >> 4, v = gid & 15;
    float as = 0.f, a0 = 0.f, a1 = 0.f, a2 = 0.f;
    const float* rp = raw + n * 64;
#pragma unroll
    for (int u = 0; u < 16; ++u) {
        float w1 = wls[u * 16 + v];
        float w2 = wlv[u * 16 + v];
        as = fmaf(rp[u], w1, as);
        a0 = fmaf(rp[16 + u * 3 + 0], w2, a0);
        a1 = fmaf(rp[16 + u * 3 + 1], w2, a1);
        a2 = fmaf(rp[16 + u * 3 + 2], w2, a2);
    }
    ls[n * 16 + v] = as * SC_ENV;
    lv[n * 48 + v * 3 + 0] = a0 * SC_ENV;
    lv[n * 48 + v * 3 + 1] = a1 * SC_ENV;
    lv[n * 48 + v * 3 + 2] = a2 * SC_ENV;
}

// =====================================================================
// K3: layer0 role-split. blockIdx&1==0: fold (gw1 + prefetch-pipelined gw2).
//                        blockIdx&1==1: latent (lat1/e1 -> lat1, raw1).
// =====================================================================
__global__ __launch_bounds__(64, 2) void k_layer0(
    const float* __restrict__ g_ea, const float* __restrict__ g_eu,
    const int* __restrict__ g_eidx,
    const float* __restrict__ g_fs, const float* __restrict__ g_fv,
    float* __restrict__ gfs2, float* __restrict__ gfv2,
    const float* __restrict__ ls0, const float* __restrict__ lv0,
    const half_t* __restrict__ b_lat1w1, const half_t* __restrict__ b_lat1w2,
    const half_t* __restrict__ b_e1w1, const half_t* __restrict__ b_e1w2,
    const half_t* __restrict__ b_gw1, const half_t* __restrict__ b_gw2,
    const half_t* __restrict__ g_lat0, half_t* __restrict__ g_lat1,
    float* __restrict__ raw1, int E) {
    __shared__ half_t sS[32 * SSD];
    __shared__ half_t Vsh[32 * VPH];
    const int lane = threadIdx.x, nl = lane & 31, q = lane >> 5;
    const int bid = blockIdx.x, g = bid >> 1, role = bid & 1;
    const int e = g * 32 + nl;
    int ce = g_eidx[e];

    float lB[40];
    const half_t* gl0 = g_lat0 + (size_t)g * 4096;
#pragma unroll
    for (int h = 0; h < 8; ++h) {
        f32x4 v = ntl_f4(gl0 + ((2 * h + q) * 32 + nl) * 8);
        lB[h * 4 + 0] = v[0]; lB[h * 4 + 1] = v[1];
        lB[h * 4 + 2] = v[2]; lB[h * 4 + 3] = v[3];
    }
    // gather env0: lane handles its edge, m = 8q..8q+7
#pragma unroll
    for (int mm = 0; mm < 8; ++mm) {
        int m = q * 8 + mm;
        float fs = ntl_f(g_fs + e * 16 + m);
        float fv0 = ntl_f(g_fv + e * 48 + m * 3 + 0);
        float fv1 = ntl_f(g_fv + e * 48 + m * 3 + 1);
        float fv2 = ntl_f(g_fv + e * 48 + m * 3 + 2);
        float es = ls0[ce * 16 + m];
        float ev0 = lv0[ce * 48 + m * 3 + 0];
        float ev1 = lv0[ce * 48 + m * 3 + 1];
        float ev2 = lv0[ce * 48 + m * 3 + 2];
        float s1 = fs * es;
        float s2 = (fv0 * ev0 + fv1 * ev1 + fv2 * ev2) * INV_S3;
        sS[nl * SSD + 2 * m + 0] = (half_t)s1;
        sS[nl * SSD + 2 * m + 1] = (half_t)s2;
        if (role == 0) {
            half_t* vp = Vsh + nl * VPH;
            vp[m * 3 + 0] = (half_t)(fs * ev0);
            vp[m * 3 + 1] = (half_t)(fs * ev1);
            vp[m * 3 + 2] = (half_t)(fs * ev2);
            vp[(16 + m) * 3 + 0] = (half_t)(fv0 * es);
            vp[(16 + m) * 3 + 1] = (half_t)(fv1 * es);
            vp[(16 + m) * 3 + 2] = (half_t)(fv2 * es);
            vp[(32 + m) * 3 + 0] = (half_t)((fv1 * ev2 - fv2 * ev1) * INV_S2);
            vp[(32 + m) * 3 + 1] = (half_t)((fv2 * ev0 - fv0 * ev2) * INV_S2);
            vp[(32 + m) * 3 + 2] = (half_t)((fv0 * ev1 - fv1 * ev0) * INV_S2);
        }
    }
    __syncthreads();

    // latent windows 8,9 (scalars)
#pragma unroll
    for (int j2 = 0; j2 < 4; ++j2) {
        lB[32 + j2] = ld_pk2(sS + nl * SSD + 8 * q + 2 * j2);
        lB[36 + j2] = ld_pk2(sS + nl * SSD + 16 + 8 * q + 2 * j2);
    }

    float hB[32];
    if (role == 0) {
        // ---- fold role ----
#pragma unroll
        for (int c = 0; c < 4; ++c) {  // gw1
            f32x16 d = colstage<20>(b_gw1, lB, c, nl, q);
            silu16(d);
            d2b(d, lane, q, &hB[8 * c], &hB[8 * c + 4]);
        }
        // combined fold over all 40 gw2 mtiles with 1-deep register prefetch
        float fsacc[8];
        float fvacc[8][3];
#pragma unroll
        for (int s = 0; s < 8; ++s) {
            fsacc[s] = 0.f;
            fvacc[s][0] = fvacc[s][1] = fvacc[s][2] = 0.f;
        }
        WFrag cur = ldw16(b_gw2, 0, nl, q);
        for (int c = 0; c < 40; ++c) {
            WFrag nxt = cur;
            if (c + 1 < 40) nxt = ldw16(b_gw2, c + 1, nl, q);  // in flight during mfma
            f32x16 d = mfma8w(cur, hB);
            if (c < 16) {
                int pu0 = 2 * c, pu1 = pu0 + 1;
                float S0 = (float)sS[nl * SSD + 2 * (pu0 & 15) + (pu0 >> 4)];
                float S1 = (float)sS[nl * SSD + 2 * (pu1 & 15) + (pu1 >> 4)];
#pragma unroll
                for (int r = 0; r < 16; ++r) {
                    int a = r >> 2, bb = r & 3, slot = (a & 1) * 4 + bb;
                    fsacc[slot] = fmaf((a < 2) ? S0 : S1, d[r], fsacc[slot]);
                }
            } else {
                int w0 = 2 * c - 32, w1 = w0 + 1;
                const half_t* vp = Vsh + nl * VPH;
                float V00 = (float)vp[w0 * 3], V01 = (float)vp[w0 * 3 + 1], V02 = (float)vp[w0 * 3 + 2];
                float V10 = (float)vp[w1 * 3], V11 = (float)vp[w1 * 3 + 1], V12 = (float)vp[w1 * 3 + 2];
#pragma unroll
                for (int r = 0; r < 16; ++r) {
                    int a = r >> 2, bb = r & 3, slot = (a & 1) * 4 + bb;
                    float x0 = (a < 2) ? V00 : V10;
                    float x1 = (a < 2) ? V01 : V11;
                    float x2 = (a < 2) ? V02 : V12;
                    fvacc[slot][0] = fmaf(x0, d[r], fvacc[slot][0]);
                    fvacc[slot][1] = fmaf(x1, d[r], fvacc[slot][1]);
                    fvacc[slot][2] = fmaf(x2, d[r], fvacc[slot][2]);
                }
            }
            cur = nxt;
        }
#pragma unroll
        for (int s = 0; s < 8; ++s) {
            int v = (s & 3) + 4 * q + 8 * (s >> 2);
            nts_f(fsacc[s] * SC_FS, gfs2 + e * 16 + v);
            nts_f(fvacc[s][0] * SC_FV, gfv2 + e * 48 + v * 3 + 0);
            nts_f(fvacc[s][1] * SC_FV, gfv2 + e * 48 + v * 3 + 1);
            nts_f(fvacc[s][2] * SC_FV, gfv2 + e * 48 + v * 3 + 2);
        }
    } else {
        // ---- latent role ----
        float4 ea = *reinterpret_cast<const float4*>(g_ea + e * 4);
        float cut = poly_cut(g_eu[e]);
#pragma unroll
        for (int c = 0; c < 4; ++c) {  // lat1w1
            f32x16 d = colstage<20>(b_lat1w1, lB, c, nl, q);
            silu16(d);
            d2b(d, lane, q, &hB[8 * c], &hB[8 * c + 4]);
        }
        half_t* gl1 = g_lat1 + (size_t)g * 4096;
        float sc = A_COLD * cut;
#pragma unroll
        for (int c = 0; c < 4; ++c) {  // lat1w2 + combine -> lat'
            f32x16 d = colstage<16>(b_lat1w2, hB, c, nl, q);
#pragma unroll
            for (int i = 0; i < 16; ++i) d[i] *= sc;
            float nw[8];
            d2b(d, lane, q, nw, nw + 4);
#pragma unroll
            for (int p = 0; p < 8; ++p) {
                float2 o = uph(lB[8 * c + p]);
                float2 nn2 = uph(nw[p]);
                lB[8 * c + p] = pkh(C_OLD * o.x + nn2.x, C_OLD * o.y + nn2.y);
            }
            nts_h8(mk8(&lB[8 * c]), gl1 + ((4 * c + q) * 32 + nl) * 8);
            nts_h8(mk8(&lB[8 * c + 4]), gl1 + ((4 * c + 2 + q) * 32 + nl) * 8);
        }
#pragma unroll
        for (int c = 0; c < 4; ++c) {  // e1w1 (K=128, lat' windows 0..7)
            f32x16 d = colstage<16>(b_e1w1, lB, c, nl, q);
            silu16(d);
            d2b(d, lane, q, &hB[8 * c], &hB[8 * c + 4]);
        }
        {  // e1w2 -> raw1 scatter
            f32x16 d = colstage<16>(b_e1w2, hB, 0, nl, q);
#pragma unroll
            for (int r = 0; r < 16; ++r) {
                int f = (r & 3) + 8 * (r >> 2) + 4 * q;
                int u = f >> 1;
                float val = d[r];
                if ((f & 1) == 0) {
                    atomicAdd(&raw1[ce * 64 + u], val * ea.x);
                } else {
                    atomicAdd(&raw1[ce * 64 + 16 + u * 3 + 0], val * ea.y);
                    atomicAdd(&raw1[ce * 64 + 16 + u * 3 + 1], val * ea.z);
                    atomicAdd(&raw1[ce * 64 + 16 + u * 3 + 2], val * ea.w);
                }
            }
        }
    }
}

// =====================================================================
// K5: layer1 — one wave per 32 edges; prefetch-pipelined 24-mtile fold;
// fw/fv combine in registers + shfl; direct g_out store.
// =====================================================================
__global__ __launch_bounds__(64, 2) void k_layer1(
    const int* __restrict__ g_eidx, const float* __restrict__ gfs2,
    const float* __restrict__ gfv2, const float* __restrict__ ls1,
    const float* __restrict__ lv1,
    const half_t* __restrict__ b_flw1, const half_t* __restrict__ b_flw2,
    const half_t* __restrict__ b_gw1, const half_t* __restrict__ b_gw2,
    const half_t* __restrict__ g_lat1, float* __restrict__ g_out, int E) {
    __shared__ half_t sS[32 * SSD];
    __shared__ half_t Vsh[32 * VPH];
    const int lane = threadIdx.x, nl = lane & 31, q = lane >> 5;
    const int g = blockIdx.x;
    const int e = g * 32 + nl;
    int ce = g_eidx[e];

    float lB[40];
    const half_t* gl1 = g_lat1 + (size_t)g * 4096;
#pragma unroll
    for (int h = 0; h < 8; ++h) {
        f32x4 v = ntl_f4(gl1 + ((2 * h + q) * 32 + nl) * 8);
        lB[h * 4 + 0] = v[0]; lB[h * 4 + 1] = v[1];
        lB[h * 4 + 2] = v[2]; lB[h * 4 + 3] = v[3];
    }
#pragma unroll
    for (int mm = 0; mm < 8; ++mm) {
        int m = q * 8 + mm;
        float fs = ntl_f(gfs2 + e * 16 + m);
        float fv0 = ntl_f(gfv2 + e * 48 + m * 3 + 0);
        float fv1 = ntl_f(gfv2 + e * 48 + m * 3 + 1);
        float fv2 = ntl_f(gfv2 + e * 48 + m * 3 + 2);
        float es = ls1[ce * 16 + m];
        float ev0 = lv1[ce * 48 + m * 3 + 0];
        float ev1 = lv1[ce * 48 + m * 3 + 1];
        float ev2 = lv1[ce * 48 + m * 3 + 2];
        float s1 = fs * es;
        float s2 = (fv0 * ev0 + fv1 * ev1 + fv2 * ev2) * INV_S3;
        sS[nl * SSD + 2 * m + 0] = (half_t)s1;
        sS[nl * SSD + 2 * m + 1] = (half_t)s2;
        half_t* vp = Vsh + nl * VPH;
        vp[m * 3 + 0] = (half_t)(fs * ev0);
        vp[m * 3 + 1] = (half_t)(fs * ev1);
        vp[m * 3 + 2] = (half_t)(fs * ev2);
        vp[(16 + m) * 3 + 0] = (half_t)(fv0 * es);
        vp[(16 + m) * 3 + 1] = (half_t)(fv1 * es);
        vp[(16 + m) * 3 + 2] = (half_t)(fv2 * es);
        vp[(32 + m) * 3 + 0] = (half_t)((fv1 * ev2 - fv2 * ev1) * INV_S2);
        vp[(32 + m) * 3 + 1] = (half_t)((fv2 * ev0 - fv0 * ev2) * INV_S2);
        vp[(32 + m) * 3 + 2] = (half_t)((fv0 * ev1 - fv1 * ev0) * INV_S2);
    }
    __syncthreads();

#pragma unroll
    for (int j2 = 0; j2 < 4; ++j2) {
        lB[32 + j2] = ld_pk2(sS + nl * SSD + 8 * q + 2 * j2);
        lB[36 + j2] = ld_pk2(sS + nl * SSD + 16 + 8 * q + 2 * j2);
    }

    float hB[32];
#pragma unroll
    for (int c = 0; c < 4; ++c) {  // flw1
        f32x16 d = colstage<20>(b_flw1, lB, c, nl, q);
        silu16(d);
        d2b(d, lane, q, &hB[8 * c], &hB[8 * c + 4]);
    }
    float fw[8];
    {  // flw2 (N=16)
        f32x16 d = colstage<16>(b_flw2, hB, 0, nl, q);
#pragma unroll
        for (int r = 0; r < 8; ++r) fw[r] = d[r];
    }
#pragma unroll
    for (int c = 0; c < 4; ++c) {  // gw1
        f32x16 d = colstage<20>(b_gw1, lB, c, nl, q);
        silu16(d);
        d2b(d, lane, q, &hB[8 * c], &hB[8 * c + 4]);
    }
    {  // gw2 wv fold: mtiles 16..39 with 1-deep register prefetch
        float fvacc[8][3];
#pragma unroll
        for (int s = 0; s < 8; ++s) fvacc[s][0] = fvacc[s][1] = fvacc[s][2] = 0.f;
        WFrag cur = ldw16(b_gw2, 16, nl, q);
        for (int c = 16; c < 40; ++c) {
            WFrag nxt = cur;
            if (c + 1 < 40) nxt = ldw16(b_gw2, c + 1, nl, q);
            f32x16 d = mfma8w(cur, hB);
            int w0 = 2 * c - 32, w1 = w0 + 1;
            const half_t* vp = Vsh + nl * VPH;
            float V00 = (float)vp[w0 * 3], V01 = (float)vp[w0 * 3 + 1], V02 = (float)vp[w0 * 3 + 2];
            float V10 = (float)vp[w1 * 3], V11 = (float)vp[w1 * 3 + 1], V12 = (float)vp[w1 * 3 + 2];
#pragma unroll
            for (int r = 0; r < 16; ++r) {
                int a = r >> 2, bb = r & 3, slot = (a & 1) * 4 + bb;
                float x0 = (a < 2) ? V00 : V10;
                float x1 = (a < 2) ? V01 : V11;
                float x2 = (a < 2) ? V02 : V12;
                fvacc[slot][0] = fmaf(x0, d[r], fvacc[slot][0]);
                fvacc[slot][1] = fmaf(x1, d[r], fvacc[slot][1]);
                fvacc[slot][2] = fmaf(x2, d[r], fvacc[slot][2]);
            }
            cur = nxt;
        }
        float o0 = 0.f, o1 = 0.f, o2 = 0.f;
#pragma unroll
        for (int s = 0; s < 8; ++s) {
            o0 = fmaf(fw[s], fvacc[s][0], o0);
            o1 = fmaf(fw[s], fvacc[s][1], o1);
            o2 = fmaf(fw[s], fvacc[s][2], o2);
        }
        o0 += __shfl(o0, lane ^ 32, 64);
        o1 += __shfl(o1, lane ^ 32, 64);
        o2 += __shfl(o2, lane ^ 32, 64);
        if (q == 0) {
            g_out[e * 3 + 0] = o0 * SC_OUT;
            g_out[e * 3 + 1] = o1 * SC_OUT;
            g_out[e * 3 + 2] = o2 * SC_OUT;
        }
    }
}

// =====================================================================
extern "C" void kernel_launch(void* const* d_in, const int* in_sizes, int n_in,
                              void* d_out, int out_size, void* d_ws, size_t ws_size,
                              hipStream_t stream) {
    const float* g_ea = (const float*)d_in[0];
    const float* g_na = (const float*)d_in[1];
    const float* g_emb = (const float*)d_in[2];
    const float* g_eu = (const float*)d_in[3];
    const int* g_eidx = (const int*)d_in[4];
    const float* w2b1 = (const float*)d_in[5];
    const float* w2b2 = (const float*)d_in[6];
    const float* lat1w1 = (const float*)d_in[7];
    const float* lat1w2 = (const float*)d_in[8];
    const float* e0w1 = (const float*)d_in[9];
    const float* e0w2 = (const float*)d_in[10];
    const float* e1w1 = (const float*)d_in[11];
    const float* e1w2 = (const float*)d_in[12];
    const float* l2w0w1 = (const float*)d_in[13];
    const float* l2w0w2 = (const float*)d_in[14];
    const float* l2w1w1 = (const float*)d_in[15];
    const float* l2w1w2 = (const float*)d_in[16];
    const float* envws = (const float*)d_in[17];
    const float* envwv = (const float*)d_in[18];
    const float* flw1 = (const float*)d_in[19];
    const float* flw2 = (const float*)d_in[20];
    float* out = (float*)d_out;

    const int E = in_sizes[3];       // 120000
    const int Nn = in_sizes[1] / 4;  // 5000
    const int nblk = E / 32;         // 3750
    const int nblk2 = nblk / 2;      // 1875

    float* p = (float*)d_ws;
    float* gfs = p;  p += (size_t)E * 16;
    float* gfv = p;  p += (size_t)E * 48;
    float* gfs2 = p; p += (size_t)E * 16;
    float* gfv2 = p; p += (size_t)E * 48;
    float* raw0 = p; p += (size_t)Nn * 64;
    float* raw1 = p; p += (size_t)Nn * 64;
    float* ls0 = p;  p += (size_t)Nn * 16;
    float* lv0 = p;  p += (size_t)Nn * 48;
    float* ls1 = p;  p += (size_t)Nn * 16;
    float* lv1 = p;  p += (size_t)Nn * 48;
    half_t* hp = (half_t*)p;
    half_t* lat0h = hp; hp += (size_t)nblk * 4096;
    half_t* lat1h = hp; hp += (size_t)nblk * 4096;

    const int KN[14][2] = {{16, 128}, {128, 128}, {128, 128}, {128, 64},
                           {160, 128}, {128, 128}, {128, 128}, {128, 32},
                           {160, 128}, {128, 1280}, {160, 128}, {128, 1280},
                           {160, 128}, {128, 16}};
    const float* srcs[14] = {w2b1, w2b2, e0w1, e0w2, lat1w1, lat1w2, e1w1, e1w2,
                             l2w0w1, l2w0w2, l2w1w1, l2w1w2, flw1, flw2};
    PackArgs pa;
    half_t* bptr[14];
    for (int i = 0; i < 14; ++i) {
        int K = KN[i][0], N = KN[i][1];
        int Npad = (N + 31) & ~31;
        bptr[i] = hp;
        hp += (size_t)K * Npad;
        pa.src[i] = srcs[i];
        pa.dst[i] = bptr[i];
        pa.K[i] = K;
        pa.N[i] = N;
    }

    k_pack<<<dim3(80, 14), 256, 0, stream>>>(pa);

    const int nzero = Nn * 128;  // raw0 + raw1 contiguous
    k_zero<<<(nzero + 255) / 256, 256, 0, stream>>>(raw0, nzero);

    const int nb2 = (Nn * 16 + 255) / 256;

    k_edge_front<<<nblk2, 128, 0, stream>>>(g_ea, g_na, g_emb, g_eu, g_eidx,
                                            bptr[0], bptr[1], bptr[2], bptr[3],
                                            lat0h, gfs, gfv, raw0, E);
    k_node_lin<<<nb2, 256, 0, stream>>>(raw0, envws, envwv, ls0, lv0, Nn);
    k_layer0<<<nblk * 2, 64, 0, stream>>>(g_ea, g_eu, g_eidx, gfs, gfv, gfs2, gfv2,
                                          ls0, lv0, bptr[4], bptr[5], bptr[6],
                                          bptr[7], bptr[8], bptr[9], lat0h, lat1h,
                                          raw1, E);
    k_node_lin<<<nb2, 256, 0, stream>>>(raw1, envws + 256, envwv + 256, ls1, lv1, Nn);
    k_layer1<<<nblk, 64, 0, stream>>>(g_eidx, gfs2, gfv2, ls1, lv1,
                                      bptr[12], bptr[13], bptr[10], bptr[11],
                                      lat1h, out, E);
}

// Round 12
// 792.814 us; speedup vs baseline: 1.1487x; 1.0581x over previous
//
#include <hip/hip_runtime.h>

typedef _Float16 half_t;
typedef _Float16 half8 __attribute__((ext_vector_type(8)));
typedef _Float16 half2_t __attribute__((ext_vector_type(2)));
typedef float f32x16 __attribute__((ext_vector_type(16)));
typedef float f32x4 __attribute__((ext_vector_type(4)));

#define DEVINL __device__ __forceinline__

// ---------- constants ----------
#define INV_S3 0.57735026918962576f   // 1/sqrt(3)
#define INV_S2 0.70710678118654752f   // 1/sqrt(2)
#define C_OLD  0.89442719099991588f   // 1/sqrt(1.25)
#define A_COLD 0.44721359549995794f   // 0.5/sqrt(1.25)
#define SC_ENV 0.05590169943749474f   // (1/sqrt(20)) * (1/4)
#define SC_FS  0.17677669529663688f   // 1/sqrt(32)
#define SC_FV  0.14433756729740643f   // 1/sqrt(48)
#define SC_OUT 0.03608439182435161f   // (1/4)/sqrt(48) — includes layer-1 fold scale
#define SSD 34                         // sS stride (halfs)
#define VPH 146                        // V stride (halfs)

DEVINL float silu_f(float x) { return x / (1.f + __expf(-x)); }

DEVINL float poly_cut(float u) {
    float u2 = u * u, u4 = u2 * u2, u6 = u4 * u2;
    float f = 1.f - 28.f * u6 + 48.f * u6 * u - 21.f * u6 * u2;
    return (u < 1.f) ? f : 0.f;
}

DEVINL float pkh(float a, float b) {
    half2_t h; h[0] = (half_t)a; h[1] = (half_t)b;
    return __builtin_bit_cast(float, h);
}
DEVINL float2 uph(float p) {
    half2_t h = __builtin_bit_cast(half2_t, p);
    return make_float2((float)h[0], (float)h[1]);
}
DEVINL half8 mk8(const float* w) {
    f32x4 v = {w[0], w[1], w[2], w[3]};
    return __builtin_bit_cast(half8, v);
}
DEVINL float ld_pk2(const half_t* p) {
    half2_t h; h[0] = p[0]; h[1] = p[1];
    return __builtin_bit_cast(float, h);
}
// ---- non-temporal streaming access (keep weights resident in cache) ----
DEVINL float ntl_f(const float* p) { return __builtin_nontemporal_load(p); }
DEVINL void nts_f(float v, float* p) { __builtin_nontemporal_store(v, p); }
DEVINL f32x4 ntl_f4(const void* p) {
    return __builtin_nontemporal_load((const f32x4*)p);
}
DEVINL void nts_h8(half8 v, half_t* p) {
    __builtin_nontemporal_store(v, (half8*)p);
}

// =====================================================================
// Edge-column MFMA stage: A = weights [M=features], B = edges (in regs).
// Weight pack: cell(mtile,kblk,m) at halfs[((mtile*KB+kblk)*32+m)*8+j]
// D: lane owns edge col n = lane&31; row f = (r&3) + 8*(r>>2) + 4*(lane>>5).
// =====================================================================
template <int KB>  // K/8
DEVINL f32x16 colstage(const half_t* __restrict__ Wg, const float* B, int mtile,
                       int nl, int q) {
    const half_t* ap = Wg + (((size_t)mtile * KB + q) * 32 + nl) * 8;
    f32x16 acc;
#pragma unroll
    for (int i = 0; i < 16; ++i) acc[i] = 0.f;
#pragma unroll
    for (int h = 0; h < KB / 2; ++h) {
        half8 a = *reinterpret_cast<const half8*>(ap + h * 512);
        acc = __builtin_amdgcn_mfma_f32_32x32x16_f16(a, mk8(B + h * 4), acc, 0, 0, 0);
    }
    return acc;
}

// ---- explicit register prefetch pipeline for K=128 fold stages ----
struct WFrag { half8 a[8]; };

DEVINL WFrag ldw16(const half_t* __restrict__ Wg, int mtile, int nl, int q) {
    const half_t* ap = Wg + (((size_t)mtile * 16 + q) * 32 + nl) * 8;
    WFrag f;
#pragma unroll
    for (int h = 0; h < 8; ++h)
        f.a[h] = *reinterpret_cast<const half8*>(ap + h * 512);
    return f;
}

DEVINL f32x16 mfma8w(const WFrag& f, const float* B) {
    f32x16 acc;
#pragma unroll
    for (int i = 0; i < 16; ++i) acc[i] = 0.f;
#pragma unroll
    for (int h = 0; h < 8; ++h)
        acc = __builtin_amdgcn_mfma_f32_32x32x16_f16(f.a[h], mk8(B + h * 4), acc, 0, 0, 0);
    return acc;
}

DEVINL void silu16(f32x16& a) {
#pragma unroll
    for (int i = 0; i < 16; ++i) a[i] = silu_f(a[i]);
}

// D (f32 regs) -> B-frag for next stage: two k-windows of 4 packed floats.
DEVINL void d2b(const f32x16& d, int lane, int q, float* wA, float* wB) {
    float pk[8];
#pragma unroll
    for (int a2 = 0; a2 < 4; ++a2) {
        pk[a2 * 2 + 0] = pkh(d[4 * a2 + 0], d[4 * a2 + 1]);
        pk[a2 * 2 + 1] = pkh(d[4 * a2 + 2], d[4 * a2 + 3]);
    }
#pragma unroll
    for (int t = 0; t < 2; ++t) {
        float k0 = q ? pk[(2 * t + 1) * 2 + 0] : pk[(2 * t) * 2 + 0];
        float k1 = q ? pk[(2 * t + 1) * 2 + 1] : pk[(2 * t) * 2 + 1];
        float s0 = q ? pk[(2 * t) * 2 + 0] : pk[(2 * t + 1) * 2 + 0];
        float s1 = q ? pk[(2 * t) * 2 + 1] : pk[(2 * t + 1) * 2 + 1];
        float r0 = __shfl(s0, lane ^ 32, 64);
        float r1 = __shfl(s1, lane ^ 32, 64);
        float* w = t ? wB : wA;
        w[0] = q ? r0 : k0;
        w[1] = q ? r1 : k1;
        w[2] = q ? k0 : r0;
        w[3] = q ? k1 : r1;
    }
}

// =====================================================================
__global__ __launch_bounds__(256) void k_zero(float* __restrict__ p, int n) {
    int i = blockIdx.x * 256 + threadIdx.x;
    if (i < n) p[i] = 0.f;
}

// =====================================================================
struct PackArgs {
    const float* src[14];
    half_t* dst[14];
    int K[14];
    int N[14];
};

__global__ __launch_bounds__(256) void k_pack(PackArgs pa) {
    int mi = blockIdx.y;
    int K = pa.K[mi], N = pa.N[mi];
    int Npad = (N + 31) & ~31;
    int KB = K >> 3;
    int cells = KB * Npad;
    int cell = blockIdx.x * 256 + threadIdx.x;
    if (cell >= cells) return;
    int nn = cell & 31, r2 = cell >> 5;
    int kblk = r2 % KB, ntile = r2 / KB;
    int n = ntile * 32 + nn;
    const float* W = pa.src[mi];
    half8 v;
#pragma unroll
    for (int j = 0; j < 8; ++j) {
        int k = kblk * 8 + j;
        v[j] = (half_t)((n < N) ? W[k * N + n] : 0.f);
    }
    *reinterpret_cast<half8*>(pa.dst[mi] + (size_t)cell * 8) = v;
}

// =====================================================================
// K1: front. 2 independent waves/block, 32 edges each, no LDS.
// =====================================================================
__global__ __launch_bounds__(128, 4) void k_edge_front(
    const float* __restrict__ g_ea, const float* __restrict__ g_na,
    const float* __restrict__ g_emb, const float* __restrict__ g_eu,
    const int* __restrict__ g_eidx,
    const half_t* __restrict__ b_w2b1, const half_t* __restrict__ b_w2b2,
    const half_t* __restrict__ b_e0w1, const half_t* __restrict__ b_e0w2,
    half_t* __restrict__ g_lat0, float* __restrict__ g_fs, float* __restrict__ g_fv,
    float* __restrict__ raw0, int E) {
    const int lane = threadIdx.x & 63, nl = lane & 31, q = lane >> 5;
    const int g = blockIdx.x * 2 + (threadIdx.x >> 6);
    const int e = g * 32 + nl;
    int ce = g_eidx[e];
    float4 ea = *reinterpret_cast<const float4*>(g_ea + e * 4);
    float cut = poly_cut(g_eu[e]);

    float xw[4];
    if (q == 0) {
        int ne = g_eidx[E + e];
        float4 nc = *reinterpret_cast<const float4*>(g_na + ce * 4);
        float4 nn = *reinterpret_cast<const float4*>(g_na + ne * 4);
        xw[0] = pkh(nc.x, nc.y); xw[1] = pkh(nc.z, nc.w);
        xw[2] = pkh(nn.x, nn.y); xw[3] = pkh(nn.z, nn.w);
    } else {
        f32x4 m0 = ntl_f4(g_emb + e * 8);
        f32x4 m1 = ntl_f4(g_emb + e * 8 + 4);
        xw[0] = pkh(m0[0], m0[1]); xw[1] = pkh(m0[2], m0[3]);
        xw[2] = pkh(m1[0], m1[1]); xw[3] = pkh(m1[2], m1[3]);
    }

    float hB[32], lB[32];
#pragma unroll
    for (int c = 0; c < 4; ++c) {  // w2b1: K=16
        f32x16 d = colstage<2>(b_w2b1, xw, c, nl, q);
        silu16(d);
        d2b(d, lane, q, &hB[8 * c], &hB[8 * c + 4]);
    }
    half_t* gl = g_lat0 + (size_t)g * 4096;
#pragma unroll
    for (int c = 0; c < 4; ++c) {  // w2b2 -> lat = cut*D
        f32x16 d = colstage<16>(b_w2b2, hB, c, nl, q);
#pragma unroll
        for (int i = 0; i < 16; ++i) d[i] *= cut;
        d2b(d, lane, q, &lB[8 * c], &lB[8 * c + 4]);
        nts_h8(mk8(&lB[8 * c]), gl + ((4 * c + q) * 32 + nl) * 8);
        nts_h8(mk8(&lB[8 * c + 4]), gl + ((4 * c + 2 + q) * 32 + nl) * 8);
    }
#pragma unroll
    for (int c = 0; c < 4; ++c) {  // e0w1
        f32x16 d = colstage<16>(b_e0w1, lB, c, nl, q);
        silu16(d);
        d2b(d, lane, q, &hB[8 * c], &hB[8 * c + 4]);
    }
    {  // e0w2 both mtiles interleaved
        f32x16 d0 = colstage<16>(b_e0w2, hB, 0, nl, q);
        f32x16 d1 = colstage<16>(b_e0w2, hB, 1, nl, q);
#pragma unroll
        for (int r = 0; r < 16; ++r) {
            int f = (r & 3) + 8 * (r >> 2) + 4 * q;
            int u = f >> 1;
            float v0 = d0[r], v1 = d1[r];
            if ((f & 1) == 0) {
                nts_f(v0 * ea.x, g_fs + e * 16 + u);
                atomicAdd(&raw0[ce * 64 + u], v1 * ea.x);
            } else {
                nts_f(v0 * ea.y, g_fv + e * 48 + u * 3 + 0);
                nts_f(v0 * ea.z, g_fv + e * 48 + u * 3 + 1);
                nts_f(v0 * ea.w, g_fv + e * 48 + u * 3 + 2);
                atomicAdd(&raw0[ce * 64 + 16 + u * 3 + 0], v1 * ea.y);
                atomicAdd(&raw0[ce * 64 + 16 + u * 3 + 1], v1 * ea.z);
                atomicAdd(&raw0[ce * 64 + 16 + u * 3 + 2], v1 * ea.w);
            }
        }
    }
}

// =====================================================================
// K2: per-node env linear (f32).
// =====================================================================
__global__ __launch_bounds__(256) void k_node_lin(
    const float* __restrict__ raw, const float* __restrict__ wls,
    const float* __restrict__ wlv, float* __restrict__ ls, float* __restrict__ lv,
    int Nn) {
    int gid = blockIdx.x * 256 + threadIdx.x;
    if (gid >= Nn * 16) return;
    int n = gid >> 4, v = gid & 15;
    float as = 0.f, a0 = 0.f, a1 = 0.f, a2 = 0.f;
    const float* rp = raw + n * 64;
#pragma unroll
    for (int u = 0; u < 16; ++u) {
        float w1 = wls[u * 16 + v];
        float w2 = wlv[u * 16 + v];
        as = fmaf(rp[u], w1, as);
        a0 = fmaf(rp[16 + u * 3 + 0], w2, a0);
        a1 = fmaf(rp[16 + u * 3 + 1], w2, a1);
        a2 = fmaf(rp[16 + u * 3 + 2], w2, a2);
    }
    ls[n * 16 + v] = as * SC_ENV;
    lv[n * 48 + v * 3 + 0] = a0 * SC_ENV;
    lv[n * 48 + v * 3 + 1] = a1 * SC_ENV;
    lv[n * 48 + v * 3 + 2] = a2 * SC_ENV;
}

// =====================================================================
// K3: layer0 role-split. blockIdx&1==0: fold (gw1 + pinned-prefetch gw2).
//                        blockIdx&1==1: latent (lat1/e1 -> lat1, raw1).
// =====================================================================
__global__ __launch_bounds__(64, 2) void k_layer0(
    const float* __restrict__ g_ea, const float* __restrict__ g_eu,
    const int* __restrict__ g_eidx,
    const float* __restrict__ g_fs, const float* __restrict__ g_fv,
    float* __restrict__ gfs2, float* __restrict__ gfv2,
    const float* __restrict__ ls0, const float* __restrict__ lv0,
    const half_t* __restrict__ b_lat1w1, const half_t* __restrict__ b_lat1w2,
    const half_t* __restrict__ b_e1w1, const half_t* __restrict__ b_e1w2,
    const half_t* __restrict__ b_gw1, const half_t* __restrict__ b_gw2,
    const half_t* __restrict__ g_lat0, half_t* __restrict__ g_lat1,
    float* __restrict__ raw1, int E) {
    __shared__ half_t sS[32 * SSD];
    __shared__ half_t Vsh[32 * VPH];
    const int lane = threadIdx.x, nl = lane & 31, q = lane >> 5;
    const int bid = blockIdx.x, g = bid >> 1, role = bid & 1;
    const int e = g * 32 + nl;
    int ce = g_eidx[e];

    float lB[40];
    const half_t* gl0 = g_lat0 + (size_t)g * 4096;
#pragma unroll
    for (int h = 0; h < 8; ++h) {
        f32x4 v = ntl_f4(gl0 + ((2 * h + q) * 32 + nl) * 8);
        lB[h * 4 + 0] = v[0]; lB[h * 4 + 1] = v[1];
        lB[h * 4 + 2] = v[2]; lB[h * 4 + 3] = v[3];
    }
    // gather env0: lane handles its edge, m = 8q..8q+7
#pragma unroll
    for (int mm = 0; mm < 8; ++mm) {
        int m = q * 8 + mm;
        float fs = ntl_f(g_fs + e * 16 + m);
        float fv0 = ntl_f(g_fv + e * 48 + m * 3 + 0);
        float fv1 = ntl_f(g_fv + e * 48 + m * 3 + 1);
        float fv2 = ntl_f(g_fv + e * 48 + m * 3 + 2);
        float es = ls0[ce * 16 + m];
        float ev0 = lv0[ce * 48 + m * 3 + 0];
        float ev1 = lv0[ce * 48 + m * 3 + 1];
        float ev2 = lv0[ce * 48 + m * 3 + 2];
        float s1 = fs * es;
        float s2 = (fv0 * ev0 + fv1 * ev1 + fv2 * ev2) * INV_S3;
        sS[nl * SSD + 2 * m + 0] = (half_t)s1;
        sS[nl * SSD + 2 * m + 1] = (half_t)s2;
        if (role == 0) {
            half_t* vp = Vsh + nl * VPH;
            vp[m * 3 + 0] = (half_t)(fs * ev0);
            vp[m * 3 + 1] = (half_t)(fs * ev1);
            vp[m * 3 + 2] = (half_t)(fs * ev2);
            vp[(16 + m) * 3 + 0] = (half_t)(fv0 * es);
            vp[(16 + m) * 3 + 1] = (half_t)(fv1 * es);
            vp[(16 + m) * 3 + 2] = (half_t)(fv2 * es);
            vp[(32 + m) * 3 + 0] = (half_t)((fv1 * ev2 - fv2 * ev1) * INV_S2);
            vp[(32 + m) * 3 + 1] = (half_t)((fv2 * ev0 - fv0 * ev2) * INV_S2);
            vp[(32 + m) * 3 + 2] = (half_t)((fv0 * ev1 - fv1 * ev0) * INV_S2);
        }
    }
    __syncthreads();

    // latent windows 8,9 (scalars)
#pragma unroll
    for (int j2 = 0; j2 < 4; ++j2) {
        lB[32 + j2] = ld_pk2(sS + nl * SSD + 8 * q + 2 * j2);
        lB[36 + j2] = ld_pk2(sS + nl * SSD + 16 + 8 * q + 2 * j2);
    }

    float hB[32];
    if (role == 0) {
        // ---- fold role ----
#pragma unroll
        for (int c = 0; c < 4; ++c) {  // gw1
            f32x16 d = colstage<20>(b_gw1, lB, c, nl, q);
            silu16(d);
            d2b(d, lane, q, &hB[8 * c], &hB[8 * c + 4]);
        }
        // combined fold over all 40 gw2 mtiles; 2-deep pinned register prefetch
        float fsacc[8];
        float fvacc[8][3];
#pragma unroll
        for (int s = 0; s < 8; ++s) {
            fsacc[s] = 0.f;
            fvacc[s][0] = fvacc[s][1] = fvacc[s][2] = 0.f;
        }
        WFrag w0 = ldw16(b_gw2, 0, nl, q);
        WFrag w1 = ldw16(b_gw2, 1, nl, q);
        for (int c = 0; c < 40; ++c) {
            __builtin_amdgcn_sched_barrier(0);
            WFrag wn = w1;
            if (c + 2 < 40) wn = ldw16(b_gw2, c + 2, nl, q);
            __builtin_amdgcn_sched_barrier(0);
            f32x16 d = mfma8w(w0, hB);
            if (c < 16) {
                int pu0 = 2 * c, pu1 = pu0 + 1;
                float S0 = (float)sS[nl * SSD + 2 * (pu0 & 15) + (pu0 >> 4)];
                float S1 = (float)sS[nl * SSD + 2 * (pu1 & 15) + (pu1 >> 4)];
#pragma unroll
                for (int r = 0; r < 16; ++r) {
                    int a = r >> 2, bb = r & 3, slot = (a & 1) * 4 + bb;
                    fsacc[slot] = fmaf((a < 2) ? S0 : S1, d[r], fsacc[slot]);
                }
            } else {
                int w0i = 2 * c - 32, w1i = w0i + 1;
                const half_t* vp = Vsh + nl * VPH;
                float V00 = (float)vp[w0i * 3], V01 = (float)vp[w0i * 3 + 1], V02 = (float)vp[w0i * 3 + 2];
                float V10 = (float)vp[w1i * 3], V11 = (float)vp[w1i * 3 + 1], V12 = (float)vp[w1i * 3 + 2];
#pragma unroll
                for (int r = 0; r < 16; ++r) {
                    int a = r >> 2, bb = r & 3, slot = (a & 1) * 4 + bb;
                    float x0 = (a < 2) ? V00 : V10;
                    float x1 = (a < 2) ? V01 : V11;
                    float x2 = (a < 2) ? V02 : V12;
                    fvacc[slot][0] = fmaf(x0, d[r], fvacc[slot][0]);
                    fvacc[slot][1] = fmaf(x1, d[r], fvacc[slot][1]);
                    fvacc[slot][2] = fmaf(x2, d[r], fvacc[slot][2]);
                }
            }
            w0 = w1;
            w1 = wn;
        }
#pragma unroll
        for (int s = 0; s < 8; ++s) {
            int v = (s & 3) + 4 * q + 8 * (s >> 2);
            nts_f(fsacc[s] * SC_FS, gfs2 + e * 16 + v);
            nts_f(fvacc[s][0] * SC_FV, gfv2 + e * 48 + v * 3 + 0);
            nts_f(fvacc[s][1] * SC_FV, gfv2 + e * 48 + v * 3 + 1);
            nts_f(fvacc[s][2] * SC_FV, gfv2 + e * 48 + v * 3 + 2);
        }
    } else {
        // ---- latent role ----
        float4 ea = *reinterpret_cast<const float4*>(g_ea + e * 4);
        float cut = poly_cut(g_eu[e]);
#pragma unroll
        for (int c = 0; c < 4; ++c) {  // lat1w1
            f32x16 d = colstage<20>(b_lat1w1, lB, c, nl, q);
            silu16(d);
            d2b(d, lane, q, &hB[8 * c], &hB[8 * c + 4]);
        }
        half_t* gl1 = g_lat1 + (size_t)g * 4096;
        float sc = A_COLD * cut;
#pragma unroll
        for (int c = 0; c < 4; ++c) {  // lat1w2 + combine -> lat'
            f32x16 d = colstage<16>(b_lat1w2, hB, c, nl, q);
#pragma unroll
            for (int i = 0; i < 16; ++i) d[i] *= sc;
            float nw[8];
            d2b(d, lane, q, nw, nw + 4);
#pragma unroll
            for (int p = 0; p < 8; ++p) {
                float2 o = uph(lB[8 * c + p]);
                float2 nn2 = uph(nw[p]);
                lB[8 * c + p] = pkh(C_OLD * o.x + nn2.x, C_OLD * o.y + nn2.y);
            }
            nts_h8(mk8(&lB[8 * c]), gl1 + ((4 * c + q) * 32 + nl) * 8);
            nts_h8(mk8(&lB[8 * c + 4]), gl1 + ((4 * c + 2 + q) * 32 + nl) * 8);
        }
#pragma unroll
        for (int c = 0; c < 4; ++c) {  // e1w1 (K=128, lat' windows 0..7)
            f32x16 d = colstage<16>(b_e1w1, lB, c, nl, q);
            silu16(d);
            d2b(d, lane, q, &hB[8 * c], &hB[8 * c + 4]);
        }
        {  // e1w2 -> raw1 scatter
            f32x16 d = colstage<16>(b_e1w2, hB, 0, nl, q);
#pragma unroll
            for (int r = 0; r < 16; ++r) {
                int f = (r & 3) + 8 * (r >> 2) + 4 * q;
                int u = f >> 1;
                float val = d[r];
                if ((f & 1) == 0) {
                    atomicAdd(&raw1[ce * 64 + u], val * ea.x);
                } else {
                    atomicAdd(&raw1[ce * 64 + 16 + u * 3 + 0], val * ea.y);
                    atomicAdd(&raw1[ce * 64 + 16 + u * 3 + 1], val * ea.z);
                    atomicAdd(&raw1[ce * 64 + 16 + u * 3 + 2], val * ea.w);
                }
            }
        }
    }
}

// =====================================================================
// K5: layer1 — one wave per 32 edges; pinned-prefetch 24-mtile fold;
// fw/fv combine in registers + shfl; direct g_out store.
// =====================================================================
__global__ __launch_bounds__(64, 2) void k_layer1(
    const int* __restrict__ g_eidx, const float* __restrict__ gfs2,
    const float* __restrict__ gfv2, const float* __restrict__ ls1,
    const float* __restrict__ lv1,
    const half_t* __restrict__ b_flw1, const half_t* __restrict__ b_flw2,
    const half_t* __restrict__ b_gw1, const half_t* __restrict__ b_gw2,
    const half_t* __restrict__ g_lat1, float* __restrict__ g_out, int E) {
    __shared__ half_t sS[32 * SSD];
    __shared__ half_t Vsh[32 * VPH];
    const int lane = threadIdx.x, nl = lane & 31, q = lane >> 5;
    const int g = blockIdx.x;
    const int e = g * 32 + nl;
    int ce = g_eidx[e];

    float lB[40];
    const half_t* gl1 = g_lat1 + (size_t)g * 4096;
#pragma unroll
    for (int h = 0; h < 8; ++h) {
        f32x4 v = ntl_f4(gl1 + ((2 * h + q) * 32 + nl) * 8);
        lB[h * 4 + 0] = v[0]; lB[h * 4 + 1] = v[1];
        lB[h * 4 + 2] = v[2]; lB[h * 4 + 3] = v[3];
    }
#pragma unroll
    for (int mm = 0; mm < 8; ++mm) {
        int m = q * 8 + mm;
        float fs = ntl_f(gfs2 + e * 16 + m);
        float fv0 = ntl_f(gfv2 + e * 48 + m * 3 + 0);
        float fv1 = ntl_f(gfv2 + e * 48 + m * 3 + 1);
        float fv2 = ntl_f(gfv2 + e * 48 + m * 3 + 2);
        float es = ls1[ce * 16 + m];
        float ev0 = lv1[ce * 48 + m * 3 + 0];
        float ev1 = lv1[ce * 48 + m * 3 + 1];
        float ev2 = lv1[ce * 48 + m * 3 + 2];
        float s1 = fs * es;
        float s2 = (fv0 * ev0 + fv1 * ev1 + fv2 * ev2) * INV_S3;
        sS[nl * SSD + 2 * m + 0] = (half_t)s1;
        sS[nl * SSD + 2 * m + 1] = (half_t)s2;
        half_t* vp = Vsh + nl * VPH;
        vp[m * 3 + 0] = (half_t)(fs * ev0);
        vp[m * 3 + 1] = (half_t)(fs * ev1);
        vp[m * 3 + 2] = (half_t)(fs * ev2);
        vp[(16 + m) * 3 + 0] = (half_t)(fv0 * es);
        vp[(16 + m) * 3 + 1] = (half_t)(fv1 * es);
        vp[(16 + m) * 3 + 2] = (half_t)(fv2 * es);
        vp[(32 + m) * 3 + 0] = (half_t)((fv1 * ev2 - fv2 * ev1) * INV_S2);
        vp[(32 + m) * 3 + 1] = (half_t)((fv2 * ev0 - fv0 * ev2) * INV_S2);
        vp[(32 + m) * 3 + 2] = (half_t)((fv0 * ev1 - fv1 * ev0) * INV_S2);
    }
    __syncthreads();

#pragma unroll
    for (int j2 = 0; j2 < 4; ++j2) {
        lB[32 + j2] = ld_pk2(sS + nl * SSD + 8 * q + 2 * j2);
        lB[36 + j2] = ld_pk2(sS + nl * SSD + 16 + 8 * q + 2 * j2);
    }

    float hB[32];
#pragma unroll
    for (int c = 0; c < 4; ++c) {  // flw1
        f32x16 d = colstage<20>(b_flw1, lB, c, nl, q);
        silu16(d);
        d2b(d, lane, q, &hB[8 * c], &hB[8 * c + 4]);
    }
    float fw[8];
    {  // flw2 (N=16)
        f32x16 d = colstage<16>(b_flw2, hB, 0, nl, q);
#pragma unroll
        for (int r = 0; r < 8; ++r) fw[r] = d[r];
    }
#pragma unroll
    for (int c = 0; c < 4; ++c) {  // gw1
        f32x16 d = colstage<20>(b_gw1, lB, c, nl, q);
        silu16(d);
        d2b(d, lane, q, &hB[8 * c], &hB[8 * c + 4]);
    }
    {  // gw2 wv fold: mtiles 16..39 with 2-deep pinned register prefetch
        float fvacc[8][3];
#pragma unroll
        for (int s = 0; s < 8; ++s) fvacc[s][0] = fvacc[s][1] = fvacc[s][2] = 0.f;
        WFrag w0 = ldw16(b_gw2, 16, nl, q);
        WFrag w1 = ldw16(b_gw2, 17, nl, q);
        for (int c = 16; c < 40; ++c) {
            __builtin_amdgcn_sched_barrier(0);
            WFrag wn = w1;
            if (c + 2 < 40) wn = ldw16(b_gw2, c + 2, nl, q);
            __builtin_amdgcn_sched_barrier(0);
            f32x16 d = mfma8w(w0, hB);
            int w0i = 2 * c - 32, w1i = w0i + 1;
            const half_t* vp = Vsh + nl * VPH;
            float V00 = (float)vp[w0i * 3], V01 = (float)vp[w0i * 3 + 1], V02 = (float)vp[w0i * 3 + 2];
            float V10 = (float)vp[w1i * 3], V11 = (float)vp[w1i * 3 + 1], V12 = (float)vp[w1i * 3 + 2];
#pragma unroll
            for (int r = 0; r < 16; ++r) {
                int a = r >> 2, bb = r & 3, slot = (a & 1) * 4 + bb;
                float x0 = (a < 2) ? V00 : V10;
                float x1 = (a < 2) ? V01 : V11;
                float x2 = (a < 2) ? V02 : V12;
                fvacc[slot][0] = fmaf(x0, d[r], fvacc[slot][0]);
                fvacc[slot][1] = fmaf(x1, d[r], fvacc[slot][1]);
                fvacc[slot][2] = fmaf(x2, d[r], fvacc[slot][2]);
            }
            w0 = w1;
            w1 = wn;
        }
        float o0 = 0.f, o1 = 0.f, o2 = 0.f;
#pragma unroll
        for (int s = 0; s < 8; ++s) {
            o0 = fmaf(fw[s], fvacc[s][0], o0);
            o1 = fmaf(fw[s], fvacc[s][1], o1);
            o2 = fmaf(fw[s], fvacc[s][2], o2);
        }
        o0 += __shfl(o0, lane ^ 32, 64);
        o1 += __shfl(o1, lane ^ 32, 64);
        o2 += __shfl(o2, lane ^ 32, 64);
        if (q == 0) {
            g_out[e * 3 + 0] = o0 * SC_OUT;
            g_out[e * 3 + 1] = o1 * SC_OUT;
            g_out[e * 3 + 2] = o2 * SC_OUT;
        }
    }
}

// =====================================================================
extern "C" void kernel_launch(void* const* d_in, const int* in_sizes, int n_in,
                              void* d_out, int out_size, void* d_ws, size_t ws_size,
                              hipStream_t stream) {
    const float* g_ea = (const float*)d_in[0];
    const float* g_na = (const float*)d_in[1];
    const float* g_emb = (const float*)d_in[2];
    const float* g_eu = (const float*)d_in[3];
    const int* g_eidx = (const int*)d_in[4];
    const float* w2b1 = (const float*)d_in[5];
    const float* w2b2 = (const float*)d_in[6];
    const float* lat1w1 = (const float*)d_in[7];
    const float* lat1w2 = (const float*)d_in[8];
    const float* e0w1 = (const float*)d_in[9];
    const float* e0w2 = (const float*)d_in[10];
    const float* e1w1 = (const float*)d_in[11];
    const float* e1w2 = (const float*)d_in[12];
    const float* l2w0w1 = (const float*)d_in[13];
    const float* l2w0w2 = (const float*)d_in[14];
    const float* l2w1w1 = (const float*)d_in[15];
    const float* l2w1w2 = (const float*)d_in[16];
    const float* envws = (const float*)d_in[17];
    const float* envwv = (const float*)d_in[18];
    const float* flw1 = (const float*)d_in[19];
    const float* flw2 = (const float*)d_in[20];
    float* out = (float*)d_out;

    const int E = in_sizes[3];       // 120000
    const int Nn = in_sizes[1] / 4;  // 5000
    const int nblk = E / 32;         // 3750
    const int nblk2 = nblk / 2;      // 1875

    float* p = (float*)d_ws;
    float* gfs = p;  p += (size_t)E * 16;
    float* gfv = p;  p += (size_t)E * 48;
    float* gfs2 = p; p += (size_t)E * 16;
    float* gfv2 = p; p += (size_t)E * 48;
    float* raw0 = p; p += (size_t)Nn * 64;
    float* raw1 = p; p += (size_t)Nn * 64;
    float* ls0 = p;  p += (size_t)Nn * 16;
    float* lv0 = p;  p += (size_t)Nn * 48;
    float* ls1 = p;  p += (size_t)Nn * 16;
    float* lv1 = p;  p += (size_t)Nn * 48;
    half_t* hp = (half_t*)p;
    half_t* lat0h = hp; hp += (size_t)nblk * 4096;
    half_t* lat1h = hp; hp += (size_t)nblk * 4096;

    const int KN[14][2] = {{16, 128}, {128, 128}, {128, 128}, {128, 64},
                           {160, 128}, {128, 128}, {128, 128}, {128, 32},
                           {160, 128}, {128, 1280}, {160, 128}, {128, 1280},
                           {160, 128}, {128, 16}};
    const float* srcs[14] = {w2b1, w2b2, e0w1, e0w2, lat1w1, lat1w2, e1w1, e1w2,
                             l2w0w1, l2w0w2, l2w1w1, l2w1w2, flw1, flw2};
    PackArgs pa;
    half_t* bptr[14];
    for (int i = 0; i < 14; ++i) {
        int K = KN[i][0], N = KN[i][1];
        int Npad = (N + 31) & ~31;
        bptr[i] = hp;
        hp += (size_t)K * Npad;
        pa.src[i] = srcs[i];
        pa.dst[i] = bptr[i];
        pa.K[i] = K;
        pa.N[i] = N;
    }

    k_pack<<<dim3(80, 14), 256, 0, stream>>>(pa);

    const int nzero = Nn * 128;  // raw0 + raw1 contiguous
    k_zero<<<(nzero + 255) / 256, 256, 0, stream>>>(raw0, nzero);

    const int nb2 = (Nn * 16 + 255) / 256;

    k_edge_front<<<nblk2, 128, 0, stream>>>(g_ea, g_na, g_emb, g_eu, g_eidx,
                                            bptr[0], bptr[1], bptr[2], bptr[3],
                                            lat0h, gfs, gfv, raw0, E);
    k_node_lin<<<nb2, 256, 0, stream>>>(raw0, envws, envwv, ls0, lv0, Nn);
    k_layer0<<<nblk * 2, 64, 0, stream>>>(g_ea, g_eu, g_eidx, gfs, gfv, gfs2, gfv2,
                                          ls0, lv0, bptr[4], bptr[5], bptr[6],
                                          bptr[7], bptr[8], bptr[9], lat0h, lat1h,
                                          raw1, E);
    k_node_lin<<<nb2, 256, 0, stream>>>(raw1, envws + 256, envwv + 256, ls1, lv1, Nn);
    k_layer1<<<nblk, 64, 0, stream>>>(g_eidx, gfs2, gfv2, ls1, lv1,
                                      bptr[12], bptr[13], bptr[10], bptr[11],
                                      lat1h, out, E);
}